// Round 19
// baseline (257.423 us; speedup 1.0000x reference)
//
#include <hip/hip_runtime.h>
#include <math.h>

// Problem constants
#define BATCH 2
#define HW 128          // H == W
#define CDIM 256
#define LTOK 16384      // HW*HW
#define MTOK 32768      // BATCH*LTOK
#define HEADS 8
#define DH 32
#define WINSZ 8
#define NWIN 64         // tokens per window
#define HID 1024

typedef unsigned int  u32;
typedef unsigned short u16;   // bf16 storage

typedef __attribute__((ext_vector_type(8))) short bf16x8;
typedef __attribute__((ext_vector_type(4))) float f32x4;

__device__ __forceinline__ float gelu_f(float v) {
    return 0.5f * v * (1.f + erff(v * 0.70710678118654752f));
}

__device__ __forceinline__ u16 f2bf(float f) {
    u32 u = __float_as_uint(f);
    u32 r = (u + 0x7fffu + ((u >> 16) & 1u)) >> 16;   // round-to-nearest-even
    return (u16)r;
}

// ---- generic 4-wide load/store: fp32 or bf16 ------------------------------
__device__ __forceinline__ float4 ld4(const float* p) { return *(const float4*)p; }
__device__ __forceinline__ float4 ld4(const u16* p) {
    uint2 v = *(const uint2*)p;
    float4 r;
    r.x = __uint_as_float((v.x & 0xffffu) << 16);
    r.y = __uint_as_float(v.x & 0xffff0000u);
    r.z = __uint_as_float((v.y & 0xffffu) << 16);
    r.w = __uint_as_float(v.y & 0xffff0000u);
    return r;
}
__device__ __forceinline__ void st4(float* p, float4 v) { *(float4*)p = v; }
__device__ __forceinline__ void st4(u16* p, float4 v) {
    uint2 o;
    o.x = (u32)f2bf(v.x) | ((u32)f2bf(v.y) << 16);
    o.y = (u32)f2bf(v.z) | ((u32)f2bf(v.w) << 16);
    *(uint2*)p = o;
}
// ---- scalar load/store ----------------------------------------------------
__device__ __forceinline__ float lds1(const float* p) { return *p; }
__device__ __forceinline__ float lds1(const u16* p) { return __uint_as_float(((u32)*p) << 16); }
__device__ __forceinline__ void sts1(float* p, float v) { *p = v; }
__device__ __forceinline__ void sts1(u16* p, float v) { *p = f2bf(v); }

// ---- 8-wide bf16 load -> 8 floats -----------------------------------------
__device__ __forceinline__ void ld8bf(const u16* p, float* v) {
    uint4 r = *(const uint4*)p;
    v[0] = __uint_as_float((r.x & 0xffffu) << 16);
    v[1] = __uint_as_float(r.x & 0xffff0000u);
    v[2] = __uint_as_float((r.y & 0xffffu) << 16);
    v[3] = __uint_as_float(r.y & 0xffff0000u);
    v[4] = __uint_as_float((r.z & 0xffffu) << 16);
    v[5] = __uint_as_float(r.z & 0xffff0000u);
    v[6] = __uint_as_float((r.w & 0xffffu) << 16);
    v[7] = __uint_as_float(r.w & 0xffff0000u);
}

// async global->LDS, 16B per lane (dest = wave-uniform base + lane*16)
__device__ __forceinline__ void glds16(const u16* g, u16* l) {
    __builtin_amdgcn_global_load_lds(
        (const __attribute__((address_space(1))) unsigned int*)g,
        (__attribute__((address_space(3))) unsigned int*)l, 16, 0, 0);
}

// ---------------------------------------------------------------------------
// Merged weight prep: qkv_wt / proj_wt / lin1_wt transposes + dwprep in ONE
// kernel (branch uniform per block). blocks [0,192): qkv (N=768),
// [192,256): proj (N=256), [256,512): lin1 (N=1024), [512,548): dwprep.
// ---------------------------------------------------------------------------
__global__ __launch_bounds__(256) void prep_kernel(
    const float* __restrict__ qkv_w, const float* __restrict__ proj_w,
    const float* __restrict__ lin1_w, const float* __restrict__ dw_w,
    u16* __restrict__ qkv_wt, u16* __restrict__ proj_wt,
    u16* __restrict__ lin1_wt, float* __restrict__ wt9)
{
    __shared__ float t[32][33];
    int idx = blockIdx.x;
    int tid = threadIdx.x;
    if (idx >= 512) {                       // dwprep: [1024][9] -> [9][1024]
        int j = (idx - 512) * 256 + tid;
        if (j < 9 * HID) {
            int ch = j / 9, tp = j - ch * 9;
            wt9[tp * HID + ch] = dw_w[j];
        }
        return;
    }
    const float* in; u16* outp; int N, bx, by;
    if (idx < 192)      { in = qkv_w;  outp = qkv_wt;  N = 768;  bx = idx % 24;        by = idx / 24; }
    else if (idx < 256) { in = proj_w; outp = proj_wt; N = 256;  bx = (idx-192) % 8;   by = (idx-192) / 8; }
    else                { in = lin1_w; outp = lin1_wt; N = 1024; bx = (idx-256) % 32;  by = (idx-256) / 32; }
    int bn = bx * 32, bk = by * 32;
    int tx = tid & 31, ty = tid >> 5;
    #pragma unroll
    for (int i = 0; i < 32; i += 8)
        t[ty + i][tx] = in[(size_t)(bk + ty + i) * N + bn + tx];
    __syncthreads();
    #pragma unroll
    for (int i = 0; i < 32; i += 8)
        outp[(size_t)(bn + ty + i) * 256 + bk + tx] = f2bf(t[tx][ty + i]);
}

// ---------------------------------------------------------------------------
// Weight prep: fp32 [K][N] -> bf16 [N][K] (tiled LDS transpose, 32x32).
// Still used for lin2_wt (its region is hbuf until dwconv completes).
// ---------------------------------------------------------------------------
__global__ __launch_bounds__(256) void transpose_bf16_kernel(
    const float* __restrict__ in, u16* __restrict__ out, int K, int N)
{
    __shared__ float t[32][33];
    int bn = blockIdx.x * 32, bk = blockIdx.y * 32;
    int tx = threadIdx.x & 31, ty = threadIdx.x >> 5;   // 32 x 8
    #pragma unroll
    for (int i = 0; i < 32; i += 8)
        t[ty + i][tx] = in[(size_t)(bk + ty + i) * N + bn + tx];
    __syncthreads();
    #pragma unroll
    for (int i = 0; i < 32; i += 8)
        out[(size_t)(bn + ty + i) * K + bk + tx] = f2bf(t[tx][ty + i]);
}

// ---------------------------------------------------------------------------
// LayerNorm over C=256: one wave (64 lanes) per row, 4 rows per 256-thr block
// ---------------------------------------------------------------------------
template<typename TI, typename TO>
__global__ __launch_bounds__(256) void ln_kernel(
    const TI* __restrict__ x, const float* __restrict__ g,
    const float* __restrict__ b, TO* __restrict__ y)
{
    int wave = threadIdx.x >> 6;
    int lane = threadIdx.x & 63;
    int row = blockIdx.x * 4 + wave;
    const TI* xr = x + (size_t)row * CDIM;
    float4 v = ld4(&xr[lane * 4]);
    float s  = v.x + v.y + v.z + v.w;
    float s2 = v.x*v.x + v.y*v.y + v.z*v.z + v.w*v.w;
    #pragma unroll
    for (int off = 32; off > 0; off >>= 1) {
        s  += __shfl_xor(s,  off);
        s2 += __shfl_xor(s2, off);
    }
    float mu   = s * (1.f / CDIM);
    float var  = s2 * (1.f / CDIM) - mu * mu;
    float rstd = rsqrtf(var + 1e-5f);
    float4 gv = *(const float4*)&g[lane * 4];
    float4 bv = *(const float4*)&b[lane * 4];
    float4 o;
    o.x = (v.x - mu) * rstd * gv.x + bv.x;
    o.y = (v.y - mu) * rstd * gv.y + bv.y;
    o.z = (v.z - mu) * rstd * gv.z + bv.z;
    o.w = (v.w - mu) * rstd * gv.w + bv.w;
    st4(&y[(size_t)row * CDIM + lane * 4], o);
}

// ---------------------------------------------------------------------------
// MFMA bf16 GEMM, 8-wave (r18 validated): BM=128 x BN=256, 512 threads =
// 8 waves each owning the proven 64x64 / acc[4][4] / 64-VGPR shape
// (wr=wave>>2 M-half, wc=wave&3 N-quarter). LDS 48KB -> 3 blocks/CU ->
// up to 24 waves/CU (vs ~10 on the 4-wave shape; measured occ 31->42%).
// Both-sides XOR granule swizzle + XCD-bijective block swizzle.
// EPI: 0=bias, 1=+residual, 2=+GELU. K is a template param.
// r19: now used for ALL GEMMs (proj, lin1, lin2).
// ---------------------------------------------------------------------------
template<int EPI, int K, typename TR, typename TO>
__global__ __launch_bounds__(512) void mgemm8_kernel(
    const u16* __restrict__ A, const u16* __restrict__ Bt,
    const float* __restrict__ bias, const TR* __restrict__ res,
    TO* __restrict__ Cc, int N, int gx)
{
    __shared__ u16 As[128 * 64];   // 16 KB
    __shared__ u16 Bs[256 * 64];   // 32 KB

    int tid  = threadIdx.x;
    int lane = tid & 63;
    int wave = tid >> 6;            // 0..7
    int l15  = lane & 15;
    int hi   = lane >> 4;
    int wr = wave >> 2;             // 0..1 (M half)
    int wc = wave & 3;              // 0..3 (N quarter)

    int nwg = gridDim.x;
    int bid = blockIdx.x;
    int swz = (bid & 7) * (nwg >> 3) + (bid >> 3);
    int bx = swz % gx, by = swz / gx;
    size_t bm = (size_t)by * 128;
    size_t bn = (size_t)bx * 256;

    int srow8 = lane >> 3;          // 0..7
    int ce    = (lane & 7) * 8;     // 0..56 (element col granule)

    int ar = wr * 64 + l15;
    int br = wc * 64 + l15;

    f32x4 acc[4][4] = {};

    for (int t = 0; t < K / 64; ++t) {
        int kt = t * 64;
        // A: 128 rows, wave stages 16 (2 glds)
        #pragma unroll
        for (int g = 0; g < 2; ++g) {
            int rowb = wave * 16 + g * 8;
            int row  = rowb + srow8;
            int col  = kt + (ce ^ ((row & 7) << 3));
            glds16(A + (bm + row) * K + col, As + rowb * 64);
        }
        // B: 256 rows, wave stages 32 (4 glds)
        #pragma unroll
        for (int g = 0; g < 4; ++g) {
            int rowb = wave * 32 + g * 8;
            int row  = rowb + srow8;
            int col  = kt + (ce ^ ((row & 7) << 3));
            glds16(Bt + (bn + row) * K + col, Bs + rowb * 64);
        }
        __syncthreads();

        #pragma unroll
        for (int ks = 0; ks < 2; ++ks) {
            int e = ks * 32 + hi * 8;
            bf16x8 af[4], bfv[4];
            #pragma unroll
            for (int m = 0; m < 4; ++m) {
                int row = ar + m * 16;
                af[m] = *(const bf16x8*)&As[row * 64 + (e ^ ((row & 7) << 3))];
            }
            #pragma unroll
            for (int n = 0; n < 4; ++n) {
                int row = br + n * 16;
                bfv[n] = *(const bf16x8*)&Bs[row * 64 + (e ^ ((row & 7) << 3))];
            }
            #pragma unroll
            for (int m = 0; m < 4; ++m)
                #pragma unroll
                for (int n = 0; n < 4; ++n)
                    acc[m][n] = __builtin_amdgcn_mfma_f32_16x16x32_bf16(
                        af[m], bfv[n], acc[m][n], 0, 0, 0);
        }
        __syncthreads();
    }

    int colb = (int)bn + wc * 64 + l15;
    int rowb = (int)bm + wr * 64 + hi * 4;
    #pragma unroll
    for (int n = 0; n < 4; ++n) {
        float bv = bias[colb + n * 16];
        #pragma unroll
        for (int m = 0; m < 4; ++m) {
            #pragma unroll
            for (int r = 0; r < 4; ++r) {
                int row = rowb + m * 16 + r;
                float v = acc[m][n][r] + bv;
                if (EPI == 1) v += lds1(&res[(size_t)row * N + colb + n * 16]);
                if (EPI == 2) v = gelu_f(v);
                sts1(&Cc[(size_t)row * N + colb + n * 16], v);
            }
        }
    }
}

// ---------------------------------------------------------------------------
// FUSED qkv-projection + windowed attention (r17 best: 512-thr, 512 blocks,
// wave=head, ZERO barriers, single merged q/k/v projection pass).
// ---------------------------------------------------------------------------
__global__ __launch_bounds__(512) void fused_qkv_attn_kernel(
    const u16* __restrict__ yn, const u16* __restrict__ qkv_wt,
    const float* __restrict__ qkv_b, const float* __restrict__ bias_table,
    u16* __restrict__ out)
{
    __shared__ u16 lds[8][4096];   // 8 KB per wave: q@0,k@2048 -> v@0 -> P@0

    int tid  = threadIdx.x;
    int lane = tid & 63;
    int head = tid >> 6;            // wave = head
    int l15  = lane & 15;
    int hi   = lane >> 4;
    int w  = blockIdx.x;            // window 0..511
    int b  = w >> 8;
    int ww = w & 255;
    int wr = ww >> 4, wc = ww & 15;
    u16* L = lds[head];

    auto tokof = [&](int n) -> int {
        int si = (wr * WINSZ + (n >> 3) + 4) & 127;
        int sj = (wc * WINSZ + (n & 7) + 4) & 127;
        return b * LTOK + si * HW + sj;
    };
    auto labelof = [&](int n) -> int {
        int i = wr * WINSZ + (n >> 3);
        int j = wc * WINSZ + (n & 7);
        int li = (i < 120) ? 0 : (i < 124 ? 1 : 2);
        int lj = (j < 120) ? 0 : (j < 124 ? 1 : 2);
        return li * 3 + lj;
    };

    const u16* arow[4];
    #pragma unroll
    for (int m = 0; m < 4; ++m)
        arow[m] = yn + (size_t)tokof(m * 16 + l15) * CDIM + hi * 8;

    // ---- merged projection pass: q,k,v in one kb loop ----------------------
    f32x4 qa[4][2] = {}, ka[4][2] = {}, va[4][2] = {};
    __builtin_amdgcn_s_setprio(1);
    #pragma unroll
    for (int kb = 0; kb < 8; ++kb) {
        bf16x8 a[4];
        #pragma unroll
        for (int m = 0; m < 4; ++m)
            a[m] = *(const bf16x8*)(arow[m] + kb * 32);
        #pragma unroll
        for (int nf = 0; nf < 2; ++nf) {
            const u16* wp = qkv_wt +
                (size_t)(head * 32 + nf * 16 + l15) * CDIM + kb * 32 + hi * 8;
            bf16x8 bq = *(const bf16x8*)wp;                 // q rows [0,256)
            bf16x8 bk = *(const bf16x8*)(wp + 256 * CDIM);  // k rows [256,512)
            bf16x8 bv = *(const bf16x8*)(wp + 512 * CDIM);  // v rows [512,768)
            #pragma unroll
            for (int m = 0; m < 4; ++m) {
                qa[m][nf] = __builtin_amdgcn_mfma_f32_16x16x32_bf16(a[m], bq, qa[m][nf], 0, 0, 0);
                ka[m][nf] = __builtin_amdgcn_mfma_f32_16x16x32_bf16(a[m], bk, ka[m][nf], 0, 0, 0);
                va[m][nf] = __builtin_amdgcn_mfma_f32_16x16x32_bf16(a[m], bv, va[m][nf], 0, 0, 0);
            }
        }
    }
    __builtin_amdgcn_s_setprio(0);

    // ---- q,k -> LDS (swizzled), read back as A/B frags ---------------------
    #pragma unroll
    for (int nf = 0; nf < 2; ++nf) {
        int d = nf * 16 + l15;
        float bq = qkv_b[head * 32 + d];
        float bk = qkv_b[256 + head * 32 + d];
        int g = nf * 2 + (l15 >> 3);
        #pragma unroll
        for (int m = 0; m < 4; ++m)
            #pragma unroll
            for (int r = 0; r < 4; ++r) {
                int tok = m * 16 + hi * 4 + r;
                int ad = tok * 32 + ((g ^ r ^ hi) << 3) + (d & 7);
                L[ad]        = f2bf(qa[m][nf][r] + bq);
                L[2048 + ad] = f2bf(ka[m][nf][r] + bk);
            }
    }
    bf16x8 qf[4], kf[4];
    {
        int sz = (hi ^ (l15 & 3) ^ ((l15 >> 2) & 3)) << 3;
        #pragma unroll
        for (int m = 0; m < 4; ++m) {
            int ra = (m * 16 + l15) * 32 + sz;
            qf[m] = *(const bf16x8*)&L[ra];
            kf[m] = *(const bf16x8*)&L[2048 + ra];
        }
    }

    // ---- v -> LDS (overlays q region, already consumed), read V^T frags ----
    #pragma unroll
    for (int nf = 0; nf < 2; ++nf) {
        int d = nf * 16 + l15;
        float bv = qkv_b[512 + head * 32 + d];
        #pragma unroll
        for (int m = 0; m < 4; ++m)
            #pragma unroll
            for (int r = 0; r < 4; ++r) {
                int tok = m * 16 + hi * 4 + r;
                int av = d * 64 + (((tok >> 3) ^ (d & 7)) << 3) + (tok & 7);
                L[av] = f2bf(va[m][nf][r] + bv);
            }
    }
    bf16x8 vf[2][2];
    #pragma unroll
    for (int nf = 0; nf < 2; ++nf) {
        int d = nf * 16 + l15;
        #pragma unroll
        for (int ks = 0; ks < 2; ++ks) {
            int rv = d * 64 + (((ks * 4 + hi) ^ (d & 7)) << 3);
            vf[nf][ks] = *(const bf16x8*)&L[rv];
        }
    }

    // ---- QK^T --------------------------------------------------------------
    f32x4 s[4][4];
    __builtin_amdgcn_s_setprio(1);
    #pragma unroll
    for (int m = 0; m < 4; ++m)
        #pragma unroll
        for (int n = 0; n < 4; ++n) {
            f32x4 z = {0.f, 0.f, 0.f, 0.f};
            s[m][n] = __builtin_amdgcn_mfma_f32_16x16x32_bf16(qf[m], kf[n], z, 0, 0, 0);
        }
    __builtin_amdgcn_s_setprio(0);

    int klbl[4];
    #pragma unroll
    for (int n = 0; n < 4; ++n) klbl[n] = labelof(n * 16 + l15);

    // ---- softmax; P -> LDS (overlays q/k/v, all consumed) ------------------
    const float SCALE = 0.17677669529663687f;  // 1/sqrt(32)
    float inv[4][4];
    #pragma unroll
    for (int m = 0; m < 4; ++m) {
        #pragma unroll
        for (int r = 0; r < 4; ++r) {
            int q = m * 16 + hi * 4 + r;
            int qlbl = labelof(q);
            int rq = q >> 3, cq = q & 7;
            float v[4];
            #pragma unroll
            for (int n = 0; n < 4; ++n) {
                int kn = n * 16 + l15;
                int idx = (rq - (kn >> 3) + 7) * 15 + (cq - (kn & 7) + 7);
                float bv = bias_table[idx * HEADS + head];
                v[n] = s[m][n][r] * SCALE + bv + ((klbl[n] != qlbl) ? -100.f : 0.f);
            }
            float rmax = fmaxf(fmaxf(v[0], v[1]), fmaxf(v[2], v[3]));
            #pragma unroll
            for (int off = 1; off < 16; off <<= 1)
                rmax = fmaxf(rmax, __shfl_xor(rmax, off));
            float p0 = __expf(v[0] - rmax), p1 = __expf(v[1] - rmax);
            float p2 = __expf(v[2] - rmax), p3 = __expf(v[3] - rmax);
            float ls = p0 + p1 + p2 + p3;
            #pragma unroll
            for (int off = 1; off < 16; off <<= 1)
                ls += __shfl_xor(ls, off);
            inv[m][r] = 1.f / ls;
            int sw = (q & 7) << 3;
            L[q * 64 + ((0 * 16 + l15) ^ sw)] = f2bf(p0);
            L[q * 64 + ((1 * 16 + l15) ^ sw)] = f2bf(p1);
            L[q * 64 + ((2 * 16 + l15) ^ sw)] = f2bf(p2);
            L[q * 64 + ((3 * 16 + l15) ^ sw)] = f2bf(p3);
        }
    }

    // ---- PV ----------------------------------------------------------------
    f32x4 o[4][2] = {};
    __builtin_amdgcn_s_setprio(1);
    #pragma unroll
    for (int ks = 0; ks < 2; ++ks) {
        #pragma unroll
        for (int m = 0; m < 4; ++m) {
            int row = m * 16 + l15;
            int colb = (ks * 32 + hi * 8) ^ ((row & 7) << 3);
            bf16x8 pa = *(const bf16x8*)&L[row * 64 + colb];
            #pragma unroll
            for (int nf = 0; nf < 2; ++nf)
                o[m][nf] = __builtin_amdgcn_mfma_f32_16x16x32_bf16(
                    pa, vf[nf][ks], o[m][nf], 0, 0, 0);
        }
    }
    __builtin_amdgcn_s_setprio(0);

    // ---- epilogue ----------------------------------------------------------
    #pragma unroll
    for (int m = 0; m < 4; ++m) {
        #pragma unroll
        for (int r = 0; r < 4; ++r) {
            int q = m * 16 + hi * 4 + r;
            int t = tokof(q);
            u16* op = out + (size_t)t * CDIM + head * DH + l15;
            float iv = inv[m][r];
            op[0]  = f2bf(o[m][0][r] * iv);
            op[16] = f2bf(o[m][1][r] * iv);
        }
    }
}

// ---------------------------------------------------------------------------
// Depthwise 3x3 conv (NHWC, SAME zero-pad) + bias + GELU. bf16 in/out.
// XCD row-locality swizzle: each XCD owns 32 contiguous image rows so halo
// rows i±1 hit the same L2.
// ---------------------------------------------------------------------------
__global__ __launch_bounds__(256) void dwconv_kernel(
    const u16* __restrict__ h, const float* __restrict__ wt9,
    const float* __restrict__ bias, u16* __restrict__ out)
{
    int bid = blockIdx.x;
    int blk = (bid & 7) * ((int)gridDim.x >> 3) + (bid >> 3);
    int b   = blk >> 11;              // b*2048 + i*16 + jt
    int rem = blk & 2047;
    int i   = rem >> 4;
    int jt  = rem & 15;
    int cg  = (threadIdx.x & 127) * 8;           // channel base (0..1016)
    int j0  = jt * 8 + (threadIdx.x >> 7) * 4;   // first of 4 output pixels

    float acc[4][8] = {};
    const u16* base = h + (size_t)b * LTOK * HID + cg;

    #pragma unroll
    for (int di = 0; di < 3; ++di) {
        int ii = i + di - 1;
        if (ii < 0 || ii >= HW) continue;
        const u16* rowp = base + (size_t)ii * HW * HID;
        float v[6][8];
        #pragma unroll
        for (int cc = 0; cc < 6; ++cc) {
            int jj = j0 - 1 + cc;
            if (jj >= 0 && jj < HW) {
                ld8bf(&rowp[(size_t)jj * HID], v[cc]);
            } else {
                #pragma unroll
                for (int q = 0; q < 8; ++q) v[cc][q] = 0.f;
            }
        }
        #pragma unroll
        for (int t = 0; t < 3; ++t) {
            const float* wp = &wt9[(di * 3 + t) * HID + cg];
            float4 wa = *(const float4*)wp;
            float4 wb = *(const float4*)(wp + 4);
            float w[8] = {wa.x, wa.y, wa.z, wa.w, wb.x, wb.y, wb.z, wb.w};
            #pragma unroll
            for (int p = 0; p < 4; ++p)
                #pragma unroll
                for (int q = 0; q < 8; ++q)
                    acc[p][q] += v[p + t][q] * w[q];
        }
    }

    float4 ba = *(const float4*)&bias[cg];
    float4 bb = *(const float4*)&bias[cg + 4];
    float bs[8] = {ba.x, ba.y, ba.z, ba.w, bb.x, bb.y, bb.z, bb.w};
    u16* ob = out + ((size_t)b * LTOK + (size_t)i * HW + j0) * HID + cg;
    #pragma unroll
    for (int p = 0; p < 4; ++p) {
        u32 o[4];
        #pragma unroll
        for (int q = 0; q < 4; ++q) {
            u16 lo = f2bf(gelu_f(acc[p][2 * q] + bs[2 * q]));
            u16 hi = f2bf(gelu_f(acc[p][2 * q + 1] + bs[2 * q + 1]));
            o[q] = (u32)lo | ((u32)hi << 16);
        }
        *(uint4*)(ob + (size_t)p * HID) = make_uint4(o[0], o[1], o[2], o[3]);
    }
}

// ---------------------------------------------------------------------------
extern "C" void kernel_launch(void* const* d_in, const int* in_sizes, int n_in,
                              void* d_out, int out_size, void* d_ws, size_t ws_size,
                              hipStream_t stream) {
    const float* x      = (const float*)d_in[0];
    const float* n1g    = (const float*)d_in[1];
    const float* n1b    = (const float*)d_in[2];
    const float* qkv_w  = (const float*)d_in[3];
    const float* qkv_b  = (const float*)d_in[4];
    const float* relb   = (const float*)d_in[5];
    const float* proj_w = (const float*)d_in[6];
    const float* proj_b = (const float*)d_in[7];
    const float* n2g    = (const float*)d_in[8];
    const float* n2b    = (const float*)d_in[9];
    const float* lin1_w = (const float*)d_in[10];
    const float* lin1_b = (const float*)d_in[11];
    const float* dw_w   = (const float*)d_in[12];
    const float* dw_b   = (const float*)d_in[13];
    const float* lin2_w = (const float*)d_in[14];
    const float* lin2_b = (const float*)d_in[15];
    float* out = (float*)d_out;

    // bf16 arena (9*M8 elems = 151 MB), fused-qkv layout (r17/r18, best):
    //  [0,M8):       yn (live to fused attn) -> yn2 -> h2[0:M8)
    //  [M8,2M8):     attn_out (fused kernel output; proj A)
    //  [2M8,..):     lin1_wt (live to lin1); then dead (h2 overwrites)
    //  [4M8,5M8):    x1 (steps proj..lin2)
    //  [5M8,9M8):    qkv_wt+proj_wt (to proj) -> hbuf (lin1..dwconv) -> lin2_wt
    u16* ws16 = (u16*)d_ws;
    const size_t M8 = (size_t)MTOK * CDIM;   // 8,388,608
    u16* yn      = ws16;
    u16* attn    = ws16 + M8;
    u16* x1      = ws16 + 4 * M8;
    u16* yn2     = ws16;
    u16* hbuf    = ws16 + 5 * M8;
    u16* h2      = ws16;
    u16* qkv_wt  = ws16 + 5 * M8;            // [768][256]
    u16* proj_wt = qkv_wt + 768 * 256;       // [256][256]
    u16* lin1_wt = ws16 + 2 * M8;            // [1024][256]
    u16* lin2_wt = ws16 + 5 * M8;            // [256][1024]
    float* wt9   = (float*)d_out;            // [9][1024] scratch; d_out dead
                                             // until final GEMM overwrites it

    // 0) merged weight prep: qkv_wt + proj_wt + lin1_wt + dwprep (one launch)
    prep_kernel<<<548, 256, 0, stream>>>(qkv_w, proj_w, lin1_w, dw_w,
                                         qkv_wt, proj_wt, lin1_wt, wt9);
    // 1) LN1: fp32 in, bf16 out
    ln_kernel<float, u16><<<MTOK / 4, 256, 0, stream>>>(x, n1g, n1b, yn);
    // 2+3) FUSED qkv projection + windowed attention (merged single pass)
    fused_qkv_attn_kernel<<<512, 512, 0, stream>>>(yn, qkv_wt, qkv_b, relb, attn);
    // 4) x1 = attn @ proj_w + proj_b + x   (8-wave: grid 1x256 = 256)
    mgemm8_kernel<1, CDIM, float, u16><<<(CDIM / 256) * (MTOK / 128), 512, 0, stream>>>(
        attn, proj_wt, proj_b, x, x1, CDIM, CDIM / 256);
    // 5) LN2: bf16 in, bf16 out
    ln_kernel<u16, u16><<<MTOK / 4, 256, 0, stream>>>(x1, n2g, n2b, yn2);
    // 6) hbuf = gelu(yn2 @ lin1_w + lin1_b)   (8-wave: grid 4x256 = 1024)
    mgemm8_kernel<2, CDIM, float, u16><<<(HID / 256) * (MTOK / 128), 512, 0, stream>>>(
        yn2, lin1_wt, lin1_b, (const float*)nullptr, hbuf, HID, HID / 256);
    // 7) h2 = gelu(dwconv3x3(hbuf) + dw_b)
    dwconv_kernel<<<BATCH * 2048, 256, 0, stream>>>(hbuf, wt9, dw_b, h2);
    // weight prep (lin2) into dead hbuf region
    transpose_bf16_kernel<<<dim3(256 / 32, 1024 / 32), 256, 0, stream>>>(lin2_w, lin2_wt, 1024, 256);
    // 8) out = h2 @ lin2_w + lin2_b + x1   (8-wave, K=1024: grid 1x256 = 256)
    mgemm8_kernel<1, HID, u16, float><<<(CDIM / 256) * (MTOK / 128), 512, 0, stream>>>(
        h2, lin2_wt, lin2_b, x1, out, CDIM, CDIM / 256);

    (void)in_sizes; (void)n_in; (void)out_size; (void)ws_size;
}

// Round 20
// 249.865 us; speedup vs baseline: 1.0302x; 1.0302x over previous
//
#include <hip/hip_runtime.h>
#include <math.h>

// Problem constants
#define BATCH 2
#define HW 128          // H == W
#define CDIM 256
#define LTOK 16384      // HW*HW
#define MTOK 32768      // BATCH*LTOK
#define HEADS 8
#define DH 32
#define WINSZ 8
#define NWIN 64         // tokens per window
#define HID 1024

typedef unsigned int  u32;
typedef unsigned short u16;   // bf16 storage

typedef __attribute__((ext_vector_type(8))) short bf16x8;
typedef __attribute__((ext_vector_type(4))) float f32x4;

__device__ __forceinline__ float gelu_f(float v) {
    return 0.5f * v * (1.f + erff(v * 0.70710678118654752f));
}

__device__ __forceinline__ u16 f2bf(float f) {
    u32 u = __float_as_uint(f);
    u32 r = (u + 0x7fffu + ((u >> 16) & 1u)) >> 16;   // round-to-nearest-even
    return (u16)r;
}

// ---- generic 4-wide load/store: fp32 or bf16 ------------------------------
__device__ __forceinline__ float4 ld4(const float* p) { return *(const float4*)p; }
__device__ __forceinline__ float4 ld4(const u16* p) {
    uint2 v = *(const uint2*)p;
    float4 r;
    r.x = __uint_as_float((v.x & 0xffffu) << 16);
    r.y = __uint_as_float(v.x & 0xffff0000u);
    r.z = __uint_as_float((v.y & 0xffffu) << 16);
    r.w = __uint_as_float(v.y & 0xffff0000u);
    return r;
}
__device__ __forceinline__ void st4(float* p, float4 v) { *(float4*)p = v; }
__device__ __forceinline__ void st4(u16* p, float4 v) {
    uint2 o;
    o.x = (u32)f2bf(v.x) | ((u32)f2bf(v.y) << 16);
    o.y = (u32)f2bf(v.z) | ((u32)f2bf(v.w) << 16);
    *(uint2*)p = o;
}
// ---- scalar load/store ----------------------------------------------------
__device__ __forceinline__ float lds1(const float* p) { return *p; }
__device__ __forceinline__ float lds1(const u16* p) { return __uint_as_float(((u32)*p) << 16); }
__device__ __forceinline__ void sts1(float* p, float v) { *p = v; }
__device__ __forceinline__ void sts1(u16* p, float v) { *p = f2bf(v); }

// ---- 8-wide bf16 load -> 8 floats -----------------------------------------
__device__ __forceinline__ void ld8bf(const u16* p, float* v) {
    uint4 r = *(const uint4*)p;
    v[0] = __uint_as_float((r.x & 0xffffu) << 16);
    v[1] = __uint_as_float(r.x & 0xffff0000u);
    v[2] = __uint_as_float((r.y & 0xffffu) << 16);
    v[3] = __uint_as_float(r.y & 0xffff0000u);
    v[4] = __uint_as_float((r.z & 0xffffu) << 16);
    v[5] = __uint_as_float(r.z & 0xffff0000u);
    v[6] = __uint_as_float((r.w & 0xffffu) << 16);
    v[7] = __uint_as_float(r.w & 0xffff0000u);
}

// async global->LDS, 16B per lane (dest = wave-uniform base + lane*16)
__device__ __forceinline__ void glds16(const u16* g, u16* l) {
    __builtin_amdgcn_global_load_lds(
        (const __attribute__((address_space(1))) unsigned int*)g,
        (__attribute__((address_space(3))) unsigned int*)l, 16, 0, 0);
}

// ---------------------------------------------------------------------------
// Merged weight prep: qkv_wt / proj_wt / lin1_wt transposes + dwprep in ONE
// kernel (branch uniform per block). blocks [0,192): qkv (N=768),
// [192,256): proj (N=256), [256,512): lin1 (N=1024), [512,548): dwprep.
// ---------------------------------------------------------------------------
__global__ __launch_bounds__(256) void prep_kernel(
    const float* __restrict__ qkv_w, const float* __restrict__ proj_w,
    const float* __restrict__ lin1_w, const float* __restrict__ dw_w,
    u16* __restrict__ qkv_wt, u16* __restrict__ proj_wt,
    u16* __restrict__ lin1_wt, float* __restrict__ wt9)
{
    __shared__ float t[32][33];
    int idx = blockIdx.x;
    int tid = threadIdx.x;
    if (idx >= 512) {                       // dwprep: [1024][9] -> [9][1024]
        int j = (idx - 512) * 256 + tid;
        if (j < 9 * HID) {
            int ch = j / 9, tp = j - ch * 9;
            wt9[tp * HID + ch] = dw_w[j];
        }
        return;
    }
    const float* in; u16* outp; int N, bx, by;
    if (idx < 192)      { in = qkv_w;  outp = qkv_wt;  N = 768;  bx = idx % 24;        by = idx / 24; }
    else if (idx < 256) { in = proj_w; outp = proj_wt; N = 256;  bx = (idx-192) % 8;   by = (idx-192) / 8; }
    else                { in = lin1_w; outp = lin1_wt; N = 1024; bx = (idx-256) % 32;  by = (idx-256) / 32; }
    int bn = bx * 32, bk = by * 32;
    int tx = tid & 31, ty = tid >> 5;
    #pragma unroll
    for (int i = 0; i < 32; i += 8)
        t[ty + i][tx] = in[(size_t)(bk + ty + i) * N + bn + tx];
    __syncthreads();
    #pragma unroll
    for (int i = 0; i < 32; i += 8)
        outp[(size_t)(bn + ty + i) * 256 + bk + tx] = f2bf(t[tx][ty + i]);
}

// ---------------------------------------------------------------------------
// Weight prep: fp32 [K][N] -> bf16 [N][K] (tiled LDS transpose, 32x32).
// Still used for lin2_wt (its region is hbuf until dwconv completes).
// ---------------------------------------------------------------------------
__global__ __launch_bounds__(256) void transpose_bf16_kernel(
    const float* __restrict__ in, u16* __restrict__ out, int K, int N)
{
    __shared__ float t[32][33];
    int bn = blockIdx.x * 32, bk = blockIdx.y * 32;
    int tx = threadIdx.x & 31, ty = threadIdx.x >> 5;   // 32 x 8
    #pragma unroll
    for (int i = 0; i < 32; i += 8)
        t[ty + i][tx] = in[(size_t)(bk + ty + i) * N + bn + tx];
    __syncthreads();
    #pragma unroll
    for (int i = 0; i < 32; i += 8)
        out[(size_t)(bn + ty + i) * K + bk + tx] = f2bf(t[tx][ty + i]);
}

// ---------------------------------------------------------------------------
// LayerNorm over C=256: one wave (64 lanes) per row, 4 rows per 256-thr block
// ---------------------------------------------------------------------------
template<typename TI, typename TO>
__global__ __launch_bounds__(256) void ln_kernel(
    const TI* __restrict__ x, const float* __restrict__ g,
    const float* __restrict__ b, TO* __restrict__ y)
{
    int wave = threadIdx.x >> 6;
    int lane = threadIdx.x & 63;
    int row = blockIdx.x * 4 + wave;
    const TI* xr = x + (size_t)row * CDIM;
    float4 v = ld4(&xr[lane * 4]);
    float s  = v.x + v.y + v.z + v.w;
    float s2 = v.x*v.x + v.y*v.y + v.z*v.z + v.w*v.w;
    #pragma unroll
    for (int off = 32; off > 0; off >>= 1) {
        s  += __shfl_xor(s,  off);
        s2 += __shfl_xor(s2, off);
    }
    float mu   = s * (1.f / CDIM);
    float var  = s2 * (1.f / CDIM) - mu * mu;
    float rstd = rsqrtf(var + 1e-5f);
    float4 gv = *(const float4*)&g[lane * 4];
    float4 bv = *(const float4*)&b[lane * 4];
    float4 o;
    o.x = (v.x - mu) * rstd * gv.x + bv.x;
    o.y = (v.y - mu) * rstd * gv.y + bv.y;
    o.z = (v.z - mu) * rstd * gv.z + bv.z;
    o.w = (v.w - mu) * rstd * gv.w + bv.w;
    st4(&y[(size_t)row * CDIM + lane * 4], o);
}

// ---------------------------------------------------------------------------
// MFMA bf16 GEMM, 4-wave (r11 structure): 128x128 tile, BK=64, single-buffer,
// XCD-bijective block swizzle + both-sides XOR granule swizzle, scalar
// epilogue. Used for proj and lin2 (their grids stay at 512 blocks -> ~2
// blocks/CU; the 8-wave tile would shrink them to 256 = 1/CU, measured worse
// in r19). EPI: 0=bias, 1=+residual, 2=+GELU. K is a template param.
// ---------------------------------------------------------------------------
template<int EPI, int K, typename TR, typename TO>
__global__ __launch_bounds__(256) void mgemm_kernel(
    const u16* __restrict__ A, const u16* __restrict__ Bt,
    const float* __restrict__ bias, const TR* __restrict__ res,
    TO* __restrict__ Cc, int N, int gx)
{
    __shared__ u16 As[128 * 64];   // 16 KB
    __shared__ u16 Bs[128 * 64];   // 16 KB

    int tid  = threadIdx.x;
    int lane = tid & 63;
    int wave = tid >> 6;
    int l15  = lane & 15;
    int hi   = lane >> 4;
    int wr = wave >> 1, wc = wave & 1;

    int nwg = gridDim.x;
    int bid = blockIdx.x;
    int swz = (bid & 7) * (nwg >> 3) + (bid >> 3);
    int bx = swz % gx, by = swz / gx;
    size_t bm = (size_t)by * 128;
    size_t bn = (size_t)bx * 128;

    int srow8 = lane >> 3;          // 0..7
    int ce    = (lane & 7) * 8;     // 0..56 (element col granule)

    int ar = wr * 64 + l15;
    int br = wc * 64 + l15;

    f32x4 acc[4][4] = {};

    for (int t = 0; t < K / 64; ++t) {
        int kt = t * 64;
        #pragma unroll
        for (int g = 0; g < 4; ++g) {
            int rowb = wave * 32 + g * 8;
            int row  = rowb + srow8;
            int col  = kt + (ce ^ ((row & 7) << 3));
            glds16(A  + (bm + row) * K + col, As + rowb * 64);
            glds16(Bt + (bn + row) * K + col, Bs + rowb * 64);
        }
        __syncthreads();

        #pragma unroll
        for (int ks = 0; ks < 2; ++ks) {
            int e = ks * 32 + hi * 8;
            bf16x8 af[4], bfv[4];
            #pragma unroll
            for (int m = 0; m < 4; ++m) {
                int row = ar + m * 16;
                af[m] = *(const bf16x8*)&As[row * 64 + (e ^ ((row & 7) << 3))];
            }
            #pragma unroll
            for (int n = 0; n < 4; ++n) {
                int row = br + n * 16;
                bfv[n] = *(const bf16x8*)&Bs[row * 64 + (e ^ ((row & 7) << 3))];
            }
            #pragma unroll
            for (int m = 0; m < 4; ++m)
                #pragma unroll
                for (int n = 0; n < 4; ++n)
                    acc[m][n] = __builtin_amdgcn_mfma_f32_16x16x32_bf16(
                        af[m], bfv[n], acc[m][n], 0, 0, 0);
        }
        __syncthreads();
    }

    int colb = (int)bn + wc * 64 + l15;
    int rowb = (int)bm + wr * 64 + hi * 4;
    #pragma unroll
    for (int n = 0; n < 4; ++n) {
        float bv = bias[colb + n * 16];
        #pragma unroll
        for (int m = 0; m < 4; ++m) {
            #pragma unroll
            for (int r = 0; r < 4; ++r) {
                int row = rowb + m * 16 + r;
                float v = acc[m][n][r] + bv;
                if (EPI == 1) v += lds1(&res[(size_t)row * N + colb + n * 16]);
                if (EPI == 2) v = gelu_f(v);
                sts1(&Cc[(size_t)row * N + colb + n * 16], v);
            }
        }
    }
}

// ---------------------------------------------------------------------------
// MFMA bf16 GEMM, 8-wave (r18 validated, lin1 ONLY): BM=128 x BN=256,
// 512 threads = 8 waves each owning the proven 64x64 / acc[4][4] / 64-VGPR
// shape. LDS 48KB -> 3 blocks/CU; lin1's grid stays 1024 blocks (4/CU
// requested) -> measured occ 31->42%, total -4.7us. r19 lesson: this tile
// is only a win when the grid still oversubscribes CUs (>= ~2x 256).
// ---------------------------------------------------------------------------
template<int EPI, int K, typename TR, typename TO>
__global__ __launch_bounds__(512) void mgemm8_kernel(
    const u16* __restrict__ A, const u16* __restrict__ Bt,
    const float* __restrict__ bias, const TR* __restrict__ res,
    TO* __restrict__ Cc, int N, int gx)
{
    __shared__ u16 As[128 * 64];   // 16 KB
    __shared__ u16 Bs[256 * 64];   // 32 KB

    int tid  = threadIdx.x;
    int lane = tid & 63;
    int wave = tid >> 6;            // 0..7
    int l15  = lane & 15;
    int hi   = lane >> 4;
    int wr = wave >> 2;             // 0..1 (M half)
    int wc = wave & 3;              // 0..3 (N quarter)

    int nwg = gridDim.x;
    int bid = blockIdx.x;
    int swz = (bid & 7) * (nwg >> 3) + (bid >> 3);
    int bx = swz % gx, by = swz / gx;
    size_t bm = (size_t)by * 128;
    size_t bn = (size_t)bx * 256;

    int srow8 = lane >> 3;          // 0..7
    int ce    = (lane & 7) * 8;     // 0..56 (element col granule)

    int ar = wr * 64 + l15;
    int br = wc * 64 + l15;

    f32x4 acc[4][4] = {};

    for (int t = 0; t < K / 64; ++t) {
        int kt = t * 64;
        // A: 128 rows, wave stages 16 (2 glds)
        #pragma unroll
        for (int g = 0; g < 2; ++g) {
            int rowb = wave * 16 + g * 8;
            int row  = rowb + srow8;
            int col  = kt + (ce ^ ((row & 7) << 3));
            glds16(A + (bm + row) * K + col, As + rowb * 64);
        }
        // B: 256 rows, wave stages 32 (4 glds)
        #pragma unroll
        for (int g = 0; g < 4; ++g) {
            int rowb = wave * 32 + g * 8;
            int row  = rowb + srow8;
            int col  = kt + (ce ^ ((row & 7) << 3));
            glds16(Bt + (bn + row) * K + col, Bs + rowb * 64);
        }
        __syncthreads();

        #pragma unroll
        for (int ks = 0; ks < 2; ++ks) {
            int e = ks * 32 + hi * 8;
            bf16x8 af[4], bfv[4];
            #pragma unroll
            for (int m = 0; m < 4; ++m) {
                int row = ar + m * 16;
                af[m] = *(const bf16x8*)&As[row * 64 + (e ^ ((row & 7) << 3))];
            }
            #pragma unroll
            for (int n = 0; n < 4; ++n) {
                int row = br + n * 16;
                bfv[n] = *(const bf16x8*)&Bs[row * 64 + (e ^ ((row & 7) << 3))];
            }
            #pragma unroll
            for (int m = 0; m < 4; ++m)
                #pragma unroll
                for (int n = 0; n < 4; ++n)
                    acc[m][n] = __builtin_amdgcn_mfma_f32_16x16x32_bf16(
                        af[m], bfv[n], acc[m][n], 0, 0, 0);
        }
        __syncthreads();
    }

    int colb = (int)bn + wc * 64 + l15;
    int rowb = (int)bm + wr * 64 + hi * 4;
    #pragma unroll
    for (int n = 0; n < 4; ++n) {
        float bv = bias[colb + n * 16];
        #pragma unroll
        for (int m = 0; m < 4; ++m) {
            #pragma unroll
            for (int r = 0; r < 4; ++r) {
                int row = rowb + m * 16 + r;
                float v = acc[m][n][r] + bv;
                if (EPI == 1) v += lds1(&res[(size_t)row * N + colb + n * 16]);
                if (EPI == 2) v = gelu_f(v);
                sts1(&Cc[(size_t)row * N + colb + n * 16], v);
            }
        }
    }
}

// ---------------------------------------------------------------------------
// FUSED qkv-projection + windowed attention (r17 best: 512-thr, 512 blocks,
// wave=head, ZERO barriers, single merged q/k/v projection pass).
// ---------------------------------------------------------------------------
__global__ __launch_bounds__(512) void fused_qkv_attn_kernel(
    const u16* __restrict__ yn, const u16* __restrict__ qkv_wt,
    const float* __restrict__ qkv_b, const float* __restrict__ bias_table,
    u16* __restrict__ out)
{
    __shared__ u16 lds[8][4096];   // 8 KB per wave: q@0,k@2048 -> v@0 -> P@0

    int tid  = threadIdx.x;
    int lane = tid & 63;
    int head = tid >> 6;            // wave = head
    int l15  = lane & 15;
    int hi   = lane >> 4;
    int w  = blockIdx.x;            // window 0..511
    int b  = w >> 8;
    int ww = w & 255;
    int wr = ww >> 4, wc = ww & 15;
    u16* L = lds[head];

    auto tokof = [&](int n) -> int {
        int si = (wr * WINSZ + (n >> 3) + 4) & 127;
        int sj = (wc * WINSZ + (n & 7) + 4) & 127;
        return b * LTOK + si * HW + sj;
    };
    auto labelof = [&](int n) -> int {
        int i = wr * WINSZ + (n >> 3);
        int j = wc * WINSZ + (n & 7);
        int li = (i < 120) ? 0 : (i < 124 ? 1 : 2);
        int lj = (j < 120) ? 0 : (j < 124 ? 1 : 2);
        return li * 3 + lj;
    };

    const u16* arow[4];
    #pragma unroll
    for (int m = 0; m < 4; ++m)
        arow[m] = yn + (size_t)tokof(m * 16 + l15) * CDIM + hi * 8;

    // ---- merged projection pass: q,k,v in one kb loop ----------------------
    f32x4 qa[4][2] = {}, ka[4][2] = {}, va[4][2] = {};
    __builtin_amdgcn_s_setprio(1);
    #pragma unroll
    for (int kb = 0; kb < 8; ++kb) {
        bf16x8 a[4];
        #pragma unroll
        for (int m = 0; m < 4; ++m)
            a[m] = *(const bf16x8*)(arow[m] + kb * 32);
        #pragma unroll
        for (int nf = 0; nf < 2; ++nf) {
            const u16* wp = qkv_wt +
                (size_t)(head * 32 + nf * 16 + l15) * CDIM + kb * 32 + hi * 8;
            bf16x8 bq = *(const bf16x8*)wp;                 // q rows [0,256)
            bf16x8 bk = *(const bf16x8*)(wp + 256 * CDIM);  // k rows [256,512)
            bf16x8 bv = *(const bf16x8*)(wp + 512 * CDIM);  // v rows [512,768)
            #pragma unroll
            for (int m = 0; m < 4; ++m) {
                qa[m][nf] = __builtin_amdgcn_mfma_f32_16x16x32_bf16(a[m], bq, qa[m][nf], 0, 0, 0);
                ka[m][nf] = __builtin_amdgcn_mfma_f32_16x16x32_bf16(a[m], bk, ka[m][nf], 0, 0, 0);
                va[m][nf] = __builtin_amdgcn_mfma_f32_16x16x32_bf16(a[m], bv, va[m][nf], 0, 0, 0);
            }
        }
    }
    __builtin_amdgcn_s_setprio(0);

    // ---- q,k -> LDS (swizzled), read back as A/B frags ---------------------
    #pragma unroll
    for (int nf = 0; nf < 2; ++nf) {
        int d = nf * 16 + l15;
        float bq = qkv_b[head * 32 + d];
        float bk = qkv_b[256 + head * 32 + d];
        int g = nf * 2 + (l15 >> 3);
        #pragma unroll
        for (int m = 0; m < 4; ++m)
            #pragma unroll
            for (int r = 0; r < 4; ++r) {
                int tok = m * 16 + hi * 4 + r;
                int ad = tok * 32 + ((g ^ r ^ hi) << 3) + (d & 7);
                L[ad]        = f2bf(qa[m][nf][r] + bq);
                L[2048 + ad] = f2bf(ka[m][nf][r] + bk);
            }
    }
    bf16x8 qf[4], kf[4];
    {
        int sz = (hi ^ (l15 & 3) ^ ((l15 >> 2) & 3)) << 3;
        #pragma unroll
        for (int m = 0; m < 4; ++m) {
            int ra = (m * 16 + l15) * 32 + sz;
            qf[m] = *(const bf16x8*)&L[ra];
            kf[m] = *(const bf16x8*)&L[2048 + ra];
        }
    }

    // ---- v -> LDS (overlays q region, already consumed), read V^T frags ----
    #pragma unroll
    for (int nf = 0; nf < 2; ++nf) {
        int d = nf * 16 + l15;
        float bv = qkv_b[512 + head * 32 + d];
        #pragma unroll
        for (int m = 0; m < 4; ++m)
            #pragma unroll
            for (int r = 0; r < 4; ++r) {
                int tok = m * 16 + hi * 4 + r;
                int av = d * 64 + (((tok >> 3) ^ (d & 7)) << 3) + (tok & 7);
                L[av] = f2bf(va[m][nf][r] + bv);
            }
    }
    bf16x8 vf[2][2];
    #pragma unroll
    for (int nf = 0; nf < 2; ++nf) {
        int d = nf * 16 + l15;
        #pragma unroll
        for (int ks = 0; ks < 2; ++ks) {
            int rv = d * 64 + (((ks * 4 + hi) ^ (d & 7)) << 3);
            vf[nf][ks] = *(const bf16x8*)&L[rv];
        }
    }

    // ---- QK^T --------------------------------------------------------------
    f32x4 s[4][4];
    __builtin_amdgcn_s_setprio(1);
    #pragma unroll
    for (int m = 0; m < 4; ++m)
        #pragma unroll
        for (int n = 0; n < 4; ++n) {
            f32x4 z = {0.f, 0.f, 0.f, 0.f};
            s[m][n] = __builtin_amdgcn_mfma_f32_16x16x32_bf16(qf[m], kf[n], z, 0, 0, 0);
        }
    __builtin_amdgcn_s_setprio(0);

    int klbl[4];
    #pragma unroll
    for (int n = 0; n < 4; ++n) klbl[n] = labelof(n * 16 + l15);

    // ---- softmax; P -> LDS (overlays q/k/v, all consumed) ------------------
    const float SCALE = 0.17677669529663687f;  // 1/sqrt(32)
    float inv[4][4];
    #pragma unroll
    for (int m = 0; m < 4; ++m) {
        #pragma unroll
        for (int r = 0; r < 4; ++r) {
            int q = m * 16 + hi * 4 + r;
            int qlbl = labelof(q);
            int rq = q >> 3, cq = q & 7;
            float v[4];
            #pragma unroll
            for (int n = 0; n < 4; ++n) {
                int kn = n * 16 + l15;
                int idx = (rq - (kn >> 3) + 7) * 15 + (cq - (kn & 7) + 7);
                float bv = bias_table[idx * HEADS + head];
                v[n] = s[m][n][r] * SCALE + bv + ((klbl[n] != qlbl) ? -100.f : 0.f);
            }
            float rmax = fmaxf(fmaxf(v[0], v[1]), fmaxf(v[2], v[3]));
            #pragma unroll
            for (int off = 1; off < 16; off <<= 1)
                rmax = fmaxf(rmax, __shfl_xor(rmax, off));
            float p0 = __expf(v[0] - rmax), p1 = __expf(v[1] - rmax);
            float p2 = __expf(v[2] - rmax), p3 = __expf(v[3] - rmax);
            float ls = p0 + p1 + p2 + p3;
            #pragma unroll
            for (int off = 1; off < 16; off <<= 1)
                ls += __shfl_xor(ls, off);
            inv[m][r] = 1.f / ls;
            int sw = (q & 7) << 3;
            L[q * 64 + ((0 * 16 + l15) ^ sw)] = f2bf(p0);
            L[q * 64 + ((1 * 16 + l15) ^ sw)] = f2bf(p1);
            L[q * 64 + ((2 * 16 + l15) ^ sw)] = f2bf(p2);
            L[q * 64 + ((3 * 16 + l15) ^ sw)] = f2bf(p3);
        }
    }

    // ---- PV ----------------------------------------------------------------
    f32x4 o[4][2] = {};
    __builtin_amdgcn_s_setprio(1);
    #pragma unroll
    for (int ks = 0; ks < 2; ++ks) {
        #pragma unroll
        for (int m = 0; m < 4; ++m) {
            int row = m * 16 + l15;
            int colb = (ks * 32 + hi * 8) ^ ((row & 7) << 3);
            bf16x8 pa = *(const bf16x8*)&L[row * 64 + colb];
            #pragma unroll
            for (int nf = 0; nf < 2; ++nf)
                o[m][nf] = __builtin_amdgcn_mfma_f32_16x16x32_bf16(
                    pa, vf[nf][ks], o[m][nf], 0, 0, 0);
        }
    }
    __builtin_amdgcn_s_setprio(0);

    // ---- epilogue ----------------------------------------------------------
    #pragma unroll
    for (int m = 0; m < 4; ++m) {
        #pragma unroll
        for (int r = 0; r < 4; ++r) {
            int q = m * 16 + hi * 4 + r;
            int t = tokof(q);
            u16* op = out + (size_t)t * CDIM + head * DH + l15;
            float iv = inv[m][r];
            op[0]  = f2bf(o[m][0][r] * iv);
            op[16] = f2bf(o[m][1][r] * iv);
        }
    }
}

// ---------------------------------------------------------------------------
// Depthwise 3x3 conv (NHWC, SAME zero-pad) + bias + GELU. bf16 in/out.
// XCD row-locality swizzle: each XCD owns 32 contiguous image rows so halo
// rows i±1 hit the same L2.
// ---------------------------------------------------------------------------
__global__ __launch_bounds__(256) void dwconv_kernel(
    const u16* __restrict__ h, const float* __restrict__ wt9,
    const float* __restrict__ bias, u16* __restrict__ out)
{
    int bid = blockIdx.x;
    int blk = (bid & 7) * ((int)gridDim.x >> 3) + (bid >> 3);
    int b   = blk >> 11;              // b*2048 + i*16 + jt
    int rem = blk & 2047;
    int i   = rem >> 4;
    int jt  = rem & 15;
    int cg  = (threadIdx.x & 127) * 8;           // channel base (0..1016)
    int j0  = jt * 8 + (threadIdx.x >> 7) * 4;   // first of 4 output pixels

    float acc[4][8] = {};
    const u16* base = h + (size_t)b * LTOK * HID + cg;

    #pragma unroll
    for (int di = 0; di < 3; ++di) {
        int ii = i + di - 1;
        if (ii < 0 || ii >= HW) continue;
        const u16* rowp = base + (size_t)ii * HW * HID;
        float v[6][8];
        #pragma unroll
        for (int cc = 0; cc < 6; ++cc) {
            int jj = j0 - 1 + cc;
            if (jj >= 0 && jj < HW) {
                ld8bf(&rowp[(size_t)jj * HID], v[cc]);
            } else {
                #pragma unroll
                for (int q = 0; q < 8; ++q) v[cc][q] = 0.f;
            }
        }
        #pragma unroll
        for (int t = 0; t < 3; ++t) {
            const float* wp = &wt9[(di * 3 + t) * HID + cg];
            float4 wa = *(const float4*)wp;
            float4 wb = *(const float4*)(wp + 4);
            float w[8] = {wa.x, wa.y, wa.z, wa.w, wb.x, wb.y, wb.z, wb.w};
            #pragma unroll
            for (int p = 0; p < 4; ++p)
                #pragma unroll
                for (int q = 0; q < 8; ++q)
                    acc[p][q] += v[p + t][q] * w[q];
        }
    }

    float4 ba = *(const float4*)&bias[cg];
    float4 bb = *(const float4*)&bias[cg + 4];
    float bs[8] = {ba.x, ba.y, ba.z, ba.w, bb.x, bb.y, bb.z, bb.w};
    u16* ob = out + ((size_t)b * LTOK + (size_t)i * HW + j0) * HID + cg;
    #pragma unroll
    for (int p = 0; p < 4; ++p) {
        u32 o[4];
        #pragma unroll
        for (int q = 0; q < 4; ++q) {
            u16 lo = f2bf(gelu_f(acc[p][2 * q] + bs[2 * q]));
            u16 hi = f2bf(gelu_f(acc[p][2 * q + 1] + bs[2 * q + 1]));
            o[q] = (u32)lo | ((u32)hi << 16);
        }
        *(uint4*)(ob + (size_t)p * HID) = make_uint4(o[0], o[1], o[2], o[3]);
    }
}

// ---------------------------------------------------------------------------
extern "C" void kernel_launch(void* const* d_in, const int* in_sizes, int n_in,
                              void* d_out, int out_size, void* d_ws, size_t ws_size,
                              hipStream_t stream) {
    const float* x      = (const float*)d_in[0];
    const float* n1g    = (const float*)d_in[1];
    const float* n1b    = (const float*)d_in[2];
    const float* qkv_w  = (const float*)d_in[3];
    const float* qkv_b  = (const float*)d_in[4];
    const float* relb   = (const float*)d_in[5];
    const float* proj_w = (const float*)d_in[6];
    const float* proj_b = (const float*)d_in[7];
    const float* n2g    = (const float*)d_in[8];
    const float* n2b    = (const float*)d_in[9];
    const float* lin1_w = (const float*)d_in[10];
    const float* lin1_b = (const float*)d_in[11];
    const float* dw_w   = (const float*)d_in[12];
    const float* dw_b   = (const float*)d_in[13];
    const float* lin2_w = (const float*)d_in[14];
    const float* lin2_b = (const float*)d_in[15];
    float* out = (float*)d_out;

    // bf16 arena (9*M8 elems = 151 MB), fused-qkv layout (r17/r18, best):
    //  [0,M8):       yn (live to fused attn) -> yn2 -> h2[0:M8)
    //  [M8,2M8):     attn_out (fused kernel output; proj A)
    //  [2M8,..):     lin1_wt (live to lin1); then dead (h2 overwrites)
    //  [4M8,5M8):    x1 (steps proj..lin2)
    //  [5M8,9M8):    qkv_wt+proj_wt (to proj) -> hbuf (lin1..dwconv) -> lin2_wt
    u16* ws16 = (u16*)d_ws;
    const size_t M8 = (size_t)MTOK * CDIM;   // 8,388,608
    u16* yn      = ws16;
    u16* attn    = ws16 + M8;
    u16* x1      = ws16 + 4 * M8;
    u16* yn2     = ws16;
    u16* hbuf    = ws16 + 5 * M8;
    u16* h2      = ws16;
    u16* qkv_wt  = ws16 + 5 * M8;            // [768][256]
    u16* proj_wt = qkv_wt + 768 * 256;       // [256][256]
    u16* lin1_wt = ws16 + 2 * M8;            // [1024][256]
    u16* lin2_wt = ws16 + 5 * M8;            // [256][1024]
    float* wt9   = (float*)d_out;            // [9][1024] scratch; d_out dead
                                             // until final GEMM overwrites it

    // 0) merged weight prep: qkv_wt + proj_wt + lin1_wt + dwprep (one launch)
    prep_kernel<<<548, 256, 0, stream>>>(qkv_w, proj_w, lin1_w, dw_w,
                                         qkv_wt, proj_wt, lin1_wt, wt9);
    // 1) LN1: fp32 in, bf16 out
    ln_kernel<float, u16><<<MTOK / 4, 256, 0, stream>>>(x, n1g, n1b, yn);
    // 2+3) FUSED qkv projection + windowed attention (merged single pass)
    fused_qkv_attn_kernel<<<512, 512, 0, stream>>>(yn, qkv_wt, qkv_b, relb, attn);
    // 4) x1 = attn @ proj_w + proj_b + x   (4-wave: grid 2x256 = 512)
    mgemm_kernel<1, CDIM, float, u16><<<(CDIM / 128) * (MTOK / 128), 256, 0, stream>>>(
        attn, proj_wt, proj_b, x, x1, CDIM, CDIM / 128);
    // 5) LN2: bf16 in, bf16 out
    ln_kernel<u16, u16><<<MTOK / 4, 256, 0, stream>>>(x1, n2g, n2b, yn2);
    // 6) hbuf = gelu(yn2 @ lin1_w + lin1_b)   (8-wave: grid 4x256 = 1024)
    mgemm8_kernel<2, CDIM, float, u16><<<(HID / 256) * (MTOK / 128), 512, 0, stream>>>(
        yn2, lin1_wt, lin1_b, (const float*)nullptr, hbuf, HID, HID / 256);
    // 7) h2 = gelu(dwconv3x3(hbuf) + dw_b)
    dwconv_kernel<<<BATCH * 2048, 256, 0, stream>>>(hbuf, wt9, dw_b, h2);
    // weight prep (lin2) into dead hbuf region
    transpose_bf16_kernel<<<dim3(256 / 32, 1024 / 32), 256, 0, stream>>>(lin2_w, lin2_wt, 1024, 256);
    // 8) out = h2 @ lin2_w + lin2_b + x1   (4-wave, K=1024: grid 2x256 = 512)
    mgemm_kernel<1, HID, u16, float><<<(CDIM / 128) * (MTOK / 128), 256, 0, stream>>>(
        h2, lin2_wt, lin2_b, x1, out, CDIM, CDIM / 128);

    (void)in_sizes; (void)n_in; (void)out_size; (void)ws_size;
}

// Round 21
// 241.164 us; speedup vs baseline: 1.0674x; 1.0361x over previous
//
#include <hip/hip_runtime.h>
#include <math.h>

// Problem constants
#define BATCH 2
#define HW 128          // H == W
#define CDIM 256
#define LTOK 16384      // HW*HW
#define MTOK 32768      // BATCH*LTOK
#define HEADS 8
#define DH 32
#define WINSZ 8
#define NWIN 64         // tokens per window
#define HID 1024

typedef unsigned int  u32;
typedef unsigned short u16;   // bf16 storage

typedef __attribute__((ext_vector_type(8))) short bf16x8;
typedef __attribute__((ext_vector_type(4))) float f32x4;

__device__ __forceinline__ float gelu_f(float v) {
    return 0.5f * v * (1.f + erff(v * 0.70710678118654752f));
}

__device__ __forceinline__ u16 f2bf(float f) {
    u32 u = __float_as_uint(f);
    u32 r = (u + 0x7fffu + ((u >> 16) & 1u)) >> 16;   // round-to-nearest-even
    return (u16)r;
}

// ---- generic 4-wide load/store: fp32 or bf16 ------------------------------
__device__ __forceinline__ float4 ld4(const float* p) { return *(const float4*)p; }
__device__ __forceinline__ float4 ld4(const u16* p) {
    uint2 v = *(const uint2*)p;
    float4 r;
    r.x = __uint_as_float((v.x & 0xffffu) << 16);
    r.y = __uint_as_float(v.x & 0xffff0000u);
    r.z = __uint_as_float((v.y & 0xffffu) << 16);
    r.w = __uint_as_float(v.y & 0xffff0000u);
    return r;
}
__device__ __forceinline__ void st4(float* p, float4 v) { *(float4*)p = v; }
__device__ __forceinline__ void st4(u16* p, float4 v) {
    uint2 o;
    o.x = (u32)f2bf(v.x) | ((u32)f2bf(v.y) << 16);
    o.y = (u32)f2bf(v.z) | ((u32)f2bf(v.w) << 16);
    *(uint2*)p = o;
}
// ---- scalar load/store ----------------------------------------------------
__device__ __forceinline__ float lds1(const float* p) { return *p; }
__device__ __forceinline__ float lds1(const u16* p) { return __uint_as_float(((u32)*p) << 16); }
__device__ __forceinline__ void sts1(float* p, float v) { *p = v; }
__device__ __forceinline__ void sts1(u16* p, float v) { *p = f2bf(v); }

// ---- 8-wide bf16 load -> 8 floats -----------------------------------------
__device__ __forceinline__ void ld8bf(const u16* p, float* v) {
    uint4 r = *(const uint4*)p;
    v[0] = __uint_as_float((r.x & 0xffffu) << 16);
    v[1] = __uint_as_float(r.x & 0xffff0000u);
    v[2] = __uint_as_float((r.y & 0xffffu) << 16);
    v[3] = __uint_as_float(r.y & 0xffff0000u);
    v[4] = __uint_as_float((r.z & 0xffffu) << 16);
    v[5] = __uint_as_float(r.z & 0xffff0000u);
    v[6] = __uint_as_float((r.w & 0xffffu) << 16);
    v[7] = __uint_as_float(r.w & 0xffff0000u);
}

// async global->LDS, 16B per lane (dest = wave-uniform base + lane*16)
__device__ __forceinline__ void glds16(const u16* g, u16* l) {
    __builtin_amdgcn_global_load_lds(
        (const __attribute__((address_space(1))) unsigned int*)g,
        (__attribute__((address_space(3))) unsigned int*)l, 16, 0, 0);
}

// ---------------------------------------------------------------------------
// Merged prep + LN1 (r21): LN1 (8192 blocks) + the three weight transposes
// (512) + dwprep (36) in ONE 8740-block launch. prep and LN1 touch disjoint
// data and were serialized back-to-back on the stream; merging co-executes
// them (saves min(prep,LN1) + one launch). Branch is block-uniform.
//   [0,8192):     LN1 rows (4 rows / 256-thr block, fp32 in -> bf16 out)
//   [8192,8384):  qkv transpose (N=768)
//   [8384,8448):  proj transpose (N=256)
//   [8448,8704):  lin1 transpose (N=1024)
//   [8704,8740):  dwprep [1024][9] -> [9][1024]
// ---------------------------------------------------------------------------
__global__ __launch_bounds__(256) void prep_ln1_kernel(
    const float* __restrict__ x, const float* __restrict__ n1g,
    const float* __restrict__ n1b, u16* __restrict__ yn,
    const float* __restrict__ qkv_w, const float* __restrict__ proj_w,
    const float* __restrict__ lin1_w, const float* __restrict__ dw_w,
    u16* __restrict__ qkv_wt, u16* __restrict__ proj_wt,
    u16* __restrict__ lin1_wt, float* __restrict__ wt9)
{
    __shared__ float t[32][33];
    int idx = blockIdx.x;
    int tid = threadIdx.x;

    if (idx < 8192) {                       // ---- LN1 ----
        int wave = tid >> 6;
        int lane = tid & 63;
        int row = idx * 4 + wave;
        const float* xr = x + (size_t)row * CDIM;
        float4 v = ld4(&xr[lane * 4]);
        float s  = v.x + v.y + v.z + v.w;
        float s2 = v.x*v.x + v.y*v.y + v.z*v.z + v.w*v.w;
        #pragma unroll
        for (int off = 32; off > 0; off >>= 1) {
            s  += __shfl_xor(s,  off);
            s2 += __shfl_xor(s2, off);
        }
        float mu   = s * (1.f / CDIM);
        float var  = s2 * (1.f / CDIM) - mu * mu;
        float rstd = rsqrtf(var + 1e-5f);
        float4 gv = *(const float4*)&n1g[lane * 4];
        float4 bv = *(const float4*)&n1b[lane * 4];
        float4 o;
        o.x = (v.x - mu) * rstd * gv.x + bv.x;
        o.y = (v.y - mu) * rstd * gv.y + bv.y;
        o.z = (v.z - mu) * rstd * gv.z + bv.z;
        o.w = (v.w - mu) * rstd * gv.w + bv.w;
        st4(&yn[(size_t)row * CDIM + lane * 4], o);
        return;
    }
    idx -= 8192;
    if (idx >= 512) {                       // ---- dwprep ----
        int j = (idx - 512) * 256 + tid;
        if (j < 9 * HID) {
            int ch = j / 9, tp = j - ch * 9;
            wt9[tp * HID + ch] = dw_w[j];
        }
        return;
    }
    const float* in; u16* outp; int N, bx, by;  // ---- transposes ----
    if (idx < 192)      { in = qkv_w;  outp = qkv_wt;  N = 768;  bx = idx % 24;        by = idx / 24; }
    else if (idx < 256) { in = proj_w; outp = proj_wt; N = 256;  bx = (idx-192) % 8;   by = (idx-192) / 8; }
    else                { in = lin1_w; outp = lin1_wt; N = 1024; bx = (idx-256) % 32;  by = (idx-256) / 32; }
    int bn = bx * 32, bk = by * 32;
    int tx = tid & 31, ty = tid >> 5;
    #pragma unroll
    for (int i = 0; i < 32; i += 8)
        t[ty + i][tx] = in[(size_t)(bk + ty + i) * N + bn + tx];
    __syncthreads();
    #pragma unroll
    for (int i = 0; i < 32; i += 8)
        outp[(size_t)(bn + ty + i) * 256 + bk + tx] = f2bf(t[tx][ty + i]);
}

// ---------------------------------------------------------------------------
// Weight prep: fp32 [K][N] -> bf16 [N][K] (tiled LDS transpose, 32x32).
// Still used for lin2_wt (its region is hbuf until dwconv completes).
// ---------------------------------------------------------------------------
__global__ __launch_bounds__(256) void transpose_bf16_kernel(
    const float* __restrict__ in, u16* __restrict__ out, int K, int N)
{
    __shared__ float t[32][33];
    int bn = blockIdx.x * 32, bk = blockIdx.y * 32;
    int tx = threadIdx.x & 31, ty = threadIdx.x >> 5;   // 32 x 8
    #pragma unroll
    for (int i = 0; i < 32; i += 8)
        t[ty + i][tx] = in[(size_t)(bk + ty + i) * N + bn + tx];
    __syncthreads();
    #pragma unroll
    for (int i = 0; i < 32; i += 8)
        out[(size_t)(bn + ty + i) * K + bk + tx] = f2bf(t[tx][ty + i]);
}

// ---------------------------------------------------------------------------
// LayerNorm over C=256 (LN2): one wave per row, 4 rows per 256-thr block
// ---------------------------------------------------------------------------
template<typename TI, typename TO>
__global__ __launch_bounds__(256) void ln_kernel(
    const TI* __restrict__ x, const float* __restrict__ g,
    const float* __restrict__ b, TO* __restrict__ y)
{
    int wave = threadIdx.x >> 6;
    int lane = threadIdx.x & 63;
    int row = blockIdx.x * 4 + wave;
    const TI* xr = x + (size_t)row * CDIM;
    float4 v = ld4(&xr[lane * 4]);
    float s  = v.x + v.y + v.z + v.w;
    float s2 = v.x*v.x + v.y*v.y + v.z*v.z + v.w*v.w;
    #pragma unroll
    for (int off = 32; off > 0; off >>= 1) {
        s  += __shfl_xor(s,  off);
        s2 += __shfl_xor(s2, off);
    }
    float mu   = s * (1.f / CDIM);
    float var  = s2 * (1.f / CDIM) - mu * mu;
    float rstd = rsqrtf(var + 1e-5f);
    float4 gv = *(const float4*)&g[lane * 4];
    float4 bv = *(const float4*)&b[lane * 4];
    float4 o;
    o.x = (v.x - mu) * rstd * gv.x + bv.x;
    o.y = (v.y - mu) * rstd * gv.y + bv.y;
    o.z = (v.z - mu) * rstd * gv.z + bv.z;
    o.w = (v.w - mu) * rstd * gv.w + bv.w;
    st4(&y[(size_t)row * CDIM + lane * 4], o);
}

// ---------------------------------------------------------------------------
// MFMA bf16 GEMM, 4-wave (r11 structure): 128x128 tile, BK=64, single-buffer,
// XCD-bijective block swizzle + both-sides XOR granule swizzle, scalar
// epilogue. Used for proj and lin2 (grids stay 512 blocks -> ~2 blocks/CU;
// r19 showed the 8-wave tile shrinks them to 1/CU and regresses).
// ---------------------------------------------------------------------------
template<int EPI, int K, typename TR, typename TO>
__global__ __launch_bounds__(256) void mgemm_kernel(
    const u16* __restrict__ A, const u16* __restrict__ Bt,
    const float* __restrict__ bias, const TR* __restrict__ res,
    TO* __restrict__ Cc, int N, int gx)
{
    __shared__ u16 As[128 * 64];   // 16 KB
    __shared__ u16 Bs[128 * 64];   // 16 KB

    int tid  = threadIdx.x;
    int lane = tid & 63;
    int wave = tid >> 6;
    int l15  = lane & 15;
    int hi   = lane >> 4;
    int wr = wave >> 1, wc = wave & 1;

    int nwg = gridDim.x;
    int bid = blockIdx.x;
    int swz = (bid & 7) * (nwg >> 3) + (bid >> 3);
    int bx = swz % gx, by = swz / gx;
    size_t bm = (size_t)by * 128;
    size_t bn = (size_t)bx * 128;

    int srow8 = lane >> 3;          // 0..7
    int ce    = (lane & 7) * 8;     // 0..56 (element col granule)

    int ar = wr * 64 + l15;
    int br = wc * 64 + l15;

    f32x4 acc[4][4] = {};

    for (int t = 0; t < K / 64; ++t) {
        int kt = t * 64;
        #pragma unroll
        for (int g = 0; g < 4; ++g) {
            int rowb = wave * 32 + g * 8;
            int row  = rowb + srow8;
            int col  = kt + (ce ^ ((row & 7) << 3));
            glds16(A  + (bm + row) * K + col, As + rowb * 64);
            glds16(Bt + (bn + row) * K + col, Bs + rowb * 64);
        }
        __syncthreads();

        #pragma unroll
        for (int ks = 0; ks < 2; ++ks) {
            int e = ks * 32 + hi * 8;
            bf16x8 af[4], bfv[4];
            #pragma unroll
            for (int m = 0; m < 4; ++m) {
                int row = ar + m * 16;
                af[m] = *(const bf16x8*)&As[row * 64 + (e ^ ((row & 7) << 3))];
            }
            #pragma unroll
            for (int n = 0; n < 4; ++n) {
                int row = br + n * 16;
                bfv[n] = *(const bf16x8*)&Bs[row * 64 + (e ^ ((row & 7) << 3))];
            }
            #pragma unroll
            for (int m = 0; m < 4; ++m)
                #pragma unroll
                for (int n = 0; n < 4; ++n)
                    acc[m][n] = __builtin_amdgcn_mfma_f32_16x16x32_bf16(
                        af[m], bfv[n], acc[m][n], 0, 0, 0);
        }
        __syncthreads();
    }

    int colb = (int)bn + wc * 64 + l15;
    int rowb = (int)bm + wr * 64 + hi * 4;
    #pragma unroll
    for (int n = 0; n < 4; ++n) {
        float bv = bias[colb + n * 16];
        #pragma unroll
        for (int m = 0; m < 4; ++m) {
            #pragma unroll
            for (int r = 0; r < 4; ++r) {
                int row = rowb + m * 16 + r;
                float v = acc[m][n][r] + bv;
                if (EPI == 1) v += lds1(&res[(size_t)row * N + colb + n * 16]);
                if (EPI == 2) v = gelu_f(v);
                sts1(&Cc[(size_t)row * N + colb + n * 16], v);
            }
        }
    }
}

// ---------------------------------------------------------------------------
// MFMA bf16 GEMM, 8-wave (r18 validated, lin1 ONLY): BM=128 x BN=256,
// 512 threads = 8 waves each owning the proven 64x64 / acc[4][4] / 64-VGPR
// shape. LDS 48KB; lin1's grid stays 1024 blocks -> occ 42%, total -4.7us.
// r19 lesson: only a win when the grid still oversubscribes CUs.
// ---------------------------------------------------------------------------
template<int EPI, int K, typename TR, typename TO>
__global__ __launch_bounds__(512) void mgemm8_kernel(
    const u16* __restrict__ A, const u16* __restrict__ Bt,
    const float* __restrict__ bias, const TR* __restrict__ res,
    TO* __restrict__ Cc, int N, int gx)
{
    __shared__ u16 As[128 * 64];   // 16 KB
    __shared__ u16 Bs[256 * 64];   // 32 KB

    int tid  = threadIdx.x;
    int lane = tid & 63;
    int wave = tid >> 6;            // 0..7
    int l15  = lane & 15;
    int hi   = lane >> 4;
    int wr = wave >> 2;             // 0..1 (M half)
    int wc = wave & 3;              // 0..3 (N quarter)

    int nwg = gridDim.x;
    int bid = blockIdx.x;
    int swz = (bid & 7) * (nwg >> 3) + (bid >> 3);
    int bx = swz % gx, by = swz / gx;
    size_t bm = (size_t)by * 128;
    size_t bn = (size_t)bx * 256;

    int srow8 = lane >> 3;          // 0..7
    int ce    = (lane & 7) * 8;     // 0..56 (element col granule)

    int ar = wr * 64 + l15;
    int br = wc * 64 + l15;

    f32x4 acc[4][4] = {};

    for (int t = 0; t < K / 64; ++t) {
        int kt = t * 64;
        // A: 128 rows, wave stages 16 (2 glds)
        #pragma unroll
        for (int g = 0; g < 2; ++g) {
            int rowb = wave * 16 + g * 8;
            int row  = rowb + srow8;
            int col  = kt + (ce ^ ((row & 7) << 3));
            glds16(A + (bm + row) * K + col, As + rowb * 64);
        }
        // B: 256 rows, wave stages 32 (4 glds)
        #pragma unroll
        for (int g = 0; g < 4; ++g) {
            int rowb = wave * 32 + g * 8;
            int row  = rowb + srow8;
            int col  = kt + (ce ^ ((row & 7) << 3));
            glds16(Bt + (bn + row) * K + col, Bs + rowb * 64);
        }
        __syncthreads();

        #pragma unroll
        for (int ks = 0; ks < 2; ++ks) {
            int e = ks * 32 + hi * 8;
            bf16x8 af[4], bfv[4];
            #pragma unroll
            for (int m = 0; m < 4; ++m) {
                int row = ar + m * 16;
                af[m] = *(const bf16x8*)&As[row * 64 + (e ^ ((row & 7) << 3))];
            }
            #pragma unroll
            for (int n = 0; n < 4; ++n) {
                int row = br + n * 16;
                bfv[n] = *(const bf16x8*)&Bs[row * 64 + (e ^ ((row & 7) << 3))];
            }
            #pragma unroll
            for (int m = 0; m < 4; ++m)
                #pragma unroll
                for (int n = 0; n < 4; ++n)
                    acc[m][n] = __builtin_amdgcn_mfma_f32_16x16x32_bf16(
                        af[m], bfv[n], acc[m][n], 0, 0, 0);
        }
        __syncthreads();
    }

    int colb = (int)bn + wc * 64 + l15;
    int rowb = (int)bm + wr * 64 + hi * 4;
    #pragma unroll
    for (int n = 0; n < 4; ++n) {
        float bv = bias[colb + n * 16];
        #pragma unroll
        for (int m = 0; m < 4; ++m) {
            #pragma unroll
            for (int r = 0; r < 4; ++r) {
                int row = rowb + m * 16 + r;
                float v = acc[m][n][r] + bv;
                if (EPI == 1) v += lds1(&res[(size_t)row * N + colb + n * 16]);
                if (EPI == 2) v = gelu_f(v);
                sts1(&Cc[(size_t)row * N + colb + n * 16], v);
            }
        }
    }
}

// ---------------------------------------------------------------------------
// FUSED qkv-projection + windowed attention (r17 best: 512-thr, 512 blocks,
// wave=head, ZERO barriers, single merged q/k/v projection pass).
// ---------------------------------------------------------------------------
__global__ __launch_bounds__(512) void fused_qkv_attn_kernel(
    const u16* __restrict__ yn, const u16* __restrict__ qkv_wt,
    const float* __restrict__ qkv_b, const float* __restrict__ bias_table,
    u16* __restrict__ out)
{
    __shared__ u16 lds[8][4096];   // 8 KB per wave: q@0,k@2048 -> v@0 -> P@0

    int tid  = threadIdx.x;
    int lane = tid & 63;
    int head = tid >> 6;            // wave = head
    int l15  = lane & 15;
    int hi   = lane >> 4;
    int w  = blockIdx.x;            // window 0..511
    int b  = w >> 8;
    int ww = w & 255;
    int wr = ww >> 4, wc = ww & 15;
    u16* L = lds[head];

    auto tokof = [&](int n) -> int {
        int si = (wr * WINSZ + (n >> 3) + 4) & 127;
        int sj = (wc * WINSZ + (n & 7) + 4) & 127;
        return b * LTOK + si * HW + sj;
    };
    auto labelof = [&](int n) -> int {
        int i = wr * WINSZ + (n >> 3);
        int j = wc * WINSZ + (n & 7);
        int li = (i < 120) ? 0 : (i < 124 ? 1 : 2);
        int lj = (j < 120) ? 0 : (j < 124 ? 1 : 2);
        return li * 3 + lj;
    };

    const u16* arow[4];
    #pragma unroll
    for (int m = 0; m < 4; ++m)
        arow[m] = yn + (size_t)tokof(m * 16 + l15) * CDIM + hi * 8;

    // ---- merged projection pass: q,k,v in one kb loop ----------------------
    f32x4 qa[4][2] = {}, ka[4][2] = {}, va[4][2] = {};
    __builtin_amdgcn_s_setprio(1);
    #pragma unroll
    for (int kb = 0; kb < 8; ++kb) {
        bf16x8 a[4];
        #pragma unroll
        for (int m = 0; m < 4; ++m)
            a[m] = *(const bf16x8*)(arow[m] + kb * 32);
        #pragma unroll
        for (int nf = 0; nf < 2; ++nf) {
            const u16* wp = qkv_wt +
                (size_t)(head * 32 + nf * 16 + l15) * CDIM + kb * 32 + hi * 8;
            bf16x8 bq = *(const bf16x8*)wp;                 // q rows [0,256)
            bf16x8 bk = *(const bf16x8*)(wp + 256 * CDIM);  // k rows [256,512)
            bf16x8 bv = *(const bf16x8*)(wp + 512 * CDIM);  // v rows [512,768)
            #pragma unroll
            for (int m = 0; m < 4; ++m) {
                qa[m][nf] = __builtin_amdgcn_mfma_f32_16x16x32_bf16(a[m], bq, qa[m][nf], 0, 0, 0);
                ka[m][nf] = __builtin_amdgcn_mfma_f32_16x16x32_bf16(a[m], bk, ka[m][nf], 0, 0, 0);
                va[m][nf] = __builtin_amdgcn_mfma_f32_16x16x32_bf16(a[m], bv, va[m][nf], 0, 0, 0);
            }
        }
    }
    __builtin_amdgcn_s_setprio(0);

    // ---- q,k -> LDS (swizzled), read back as A/B frags ---------------------
    #pragma unroll
    for (int nf = 0; nf < 2; ++nf) {
        int d = nf * 16 + l15;
        float bq = qkv_b[head * 32 + d];
        float bk = qkv_b[256 + head * 32 + d];
        int g = nf * 2 + (l15 >> 3);
        #pragma unroll
        for (int m = 0; m < 4; ++m)
            #pragma unroll
            for (int r = 0; r < 4; ++r) {
                int tok = m * 16 + hi * 4 + r;
                int ad = tok * 32 + ((g ^ r ^ hi) << 3) + (d & 7);
                L[ad]        = f2bf(qa[m][nf][r] + bq);
                L[2048 + ad] = f2bf(ka[m][nf][r] + bk);
            }
    }
    bf16x8 qf[4], kf[4];
    {
        int sz = (hi ^ (l15 & 3) ^ ((l15 >> 2) & 3)) << 3;
        #pragma unroll
        for (int m = 0; m < 4; ++m) {
            int ra = (m * 16 + l15) * 32 + sz;
            qf[m] = *(const bf16x8*)&L[ra];
            kf[m] = *(const bf16x8*)&L[2048 + ra];
        }
    }

    // ---- v -> LDS (overlays q region, already consumed), read V^T frags ----
    #pragma unroll
    for (int nf = 0; nf < 2; ++nf) {
        int d = nf * 16 + l15;
        float bv = qkv_b[512 + head * 32 + d];
        #pragma unroll
        for (int m = 0; m < 4; ++m)
            #pragma unroll
            for (int r = 0; r < 4; ++r) {
                int tok = m * 16 + hi * 4 + r;
                int av = d * 64 + (((tok >> 3) ^ (d & 7)) << 3) + (tok & 7);
                L[av] = f2bf(va[m][nf][r] + bv);
            }
    }
    bf16x8 vf[2][2];
    #pragma unroll
    for (int nf = 0; nf < 2; ++nf) {
        int d = nf * 16 + l15;
        #pragma unroll
        for (int ks = 0; ks < 2; ++ks) {
            int rv = d * 64 + (((ks * 4 + hi) ^ (d & 7)) << 3);
            vf[nf][ks] = *(const bf16x8*)&L[rv];
        }
    }

    // ---- QK^T --------------------------------------------------------------
    f32x4 s[4][4];
    __builtin_amdgcn_s_setprio(1);
    #pragma unroll
    for (int m = 0; m < 4; ++m)
        #pragma unroll
        for (int n = 0; n < 4; ++n) {
            f32x4 z = {0.f, 0.f, 0.f, 0.f};
            s[m][n] = __builtin_amdgcn_mfma_f32_16x16x32_bf16(qf[m], kf[n], z, 0, 0, 0);
        }
    __builtin_amdgcn_s_setprio(0);

    int klbl[4];
    #pragma unroll
    for (int n = 0; n < 4; ++n) klbl[n] = labelof(n * 16 + l15);

    // ---- softmax; P -> LDS (overlays q/k/v, all consumed) ------------------
    const float SCALE = 0.17677669529663687f;  // 1/sqrt(32)
    float inv[4][4];
    #pragma unroll
    for (int m = 0; m < 4; ++m) {
        #pragma unroll
        for (int r = 0; r < 4; ++r) {
            int q = m * 16 + hi * 4 + r;
            int qlbl = labelof(q);
            int rq = q >> 3, cq = q & 7;
            float v[4];
            #pragma unroll
            for (int n = 0; n < 4; ++n) {
                int kn = n * 16 + l15;
                int idx = (rq - (kn >> 3) + 7) * 15 + (cq - (kn & 7) + 7);
                float bv = bias_table[idx * HEADS + head];
                v[n] = s[m][n][r] * SCALE + bv + ((klbl[n] != qlbl) ? -100.f : 0.f);
            }
            float rmax = fmaxf(fmaxf(v[0], v[1]), fmaxf(v[2], v[3]));
            #pragma unroll
            for (int off = 1; off < 16; off <<= 1)
                rmax = fmaxf(rmax, __shfl_xor(rmax, off));
            float p0 = __expf(v[0] - rmax), p1 = __expf(v[1] - rmax);
            float p2 = __expf(v[2] - rmax), p3 = __expf(v[3] - rmax);
            float ls = p0 + p1 + p2 + p3;
            #pragma unroll
            for (int off = 1; off < 16; off <<= 1)
                ls += __shfl_xor(ls, off);
            inv[m][r] = 1.f / ls;
            int sw = (q & 7) << 3;
            L[q * 64 + ((0 * 16 + l15) ^ sw)] = f2bf(p0);
            L[q * 64 + ((1 * 16 + l15) ^ sw)] = f2bf(p1);
            L[q * 64 + ((2 * 16 + l15) ^ sw)] = f2bf(p2);
            L[q * 64 + ((3 * 16 + l15) ^ sw)] = f2bf(p3);
        }
    }

    // ---- PV ----------------------------------------------------------------
    f32x4 o[4][2] = {};
    __builtin_amdgcn_s_setprio(1);
    #pragma unroll
    for (int ks = 0; ks < 2; ++ks) {
        #pragma unroll
        for (int m = 0; m < 4; ++m) {
            int row = m * 16 + l15;
            int colb = (ks * 32 + hi * 8) ^ ((row & 7) << 3);
            bf16x8 pa = *(const bf16x8*)&L[row * 64 + colb];
            #pragma unroll
            for (int nf = 0; nf < 2; ++nf)
                o[m][nf] = __builtin_amdgcn_mfma_f32_16x16x32_bf16(
                    pa, vf[nf][ks], o[m][nf], 0, 0, 0);
        }
    }
    __builtin_amdgcn_s_setprio(0);

    // ---- epilogue ----------------------------------------------------------
    #pragma unroll
    for (int m = 0; m < 4; ++m) {
        #pragma unroll
        for (int r = 0; r < 4; ++r) {
            int q = m * 16 + hi * 4 + r;
            int t = tokof(q);
            u16* op = out + (size_t)t * CDIM + head * DH + l15;
            float iv = inv[m][r];
            op[0]  = f2bf(o[m][0][r] * iv);
            op[16] = f2bf(o[m][1][r] * iv);
        }
    }
}

// ---------------------------------------------------------------------------
// Depthwise 3x3 conv (NHWC, SAME zero-pad) + bias + GELU. bf16 in/out.
// XCD row-locality swizzle: each XCD owns 32 contiguous image rows so halo
// rows i±1 hit the same L2.
// ---------------------------------------------------------------------------
__global__ __launch_bounds__(256) void dwconv_kernel(
    const u16* __restrict__ h, const float* __restrict__ wt9,
    const float* __restrict__ bias, u16* __restrict__ out)
{
    int bid = blockIdx.x;
    int blk = (bid & 7) * ((int)gridDim.x >> 3) + (bid >> 3);
    int b   = blk >> 11;              // b*2048 + i*16 + jt
    int rem = blk & 2047;
    int i   = rem >> 4;
    int jt  = rem & 15;
    int cg  = (threadIdx.x & 127) * 8;           // channel base (0..1016)
    int j0  = jt * 8 + (threadIdx.x >> 7) * 4;   // first of 4 output pixels

    float acc[4][8] = {};
    const u16* base = h + (size_t)b * LTOK * HID + cg;

    #pragma unroll
    for (int di = 0; di < 3; ++di) {
        int ii = i + di - 1;
        if (ii < 0 || ii >= HW) continue;
        const u16* rowp = base + (size_t)ii * HW * HID;
        float v[6][8];
        #pragma unroll
        for (int cc = 0; cc < 6; ++cc) {
            int jj = j0 - 1 + cc;
            if (jj >= 0 && jj < HW) {
                ld8bf(&rowp[(size_t)jj * HID], v[cc]);
            } else {
                #pragma unroll
                for (int q = 0; q < 8; ++q) v[cc][q] = 0.f;
            }
        }
        #pragma unroll
        for (int t = 0; t < 3; ++t) {
            const float* wp = &wt9[(di * 3 + t) * HID + cg];
            float4 wa = *(const float4*)wp;
            float4 wb = *(const float4*)(wp + 4);
            float w[8] = {wa.x, wa.y, wa.z, wa.w, wb.x, wb.y, wb.z, wb.w};
            #pragma unroll
            for (int p = 0; p < 4; ++p)
                #pragma unroll
                for (int q = 0; q < 8; ++q)
                    acc[p][q] += v[p + t][q] * w[q];
        }
    }

    float4 ba = *(const float4*)&bias[cg];
    float4 bb = *(const float4*)&bias[cg + 4];
    float bs[8] = {ba.x, ba.y, ba.z, ba.w, bb.x, bb.y, bb.z, bb.w};
    u16* ob = out + ((size_t)b * LTOK + (size_t)i * HW + j0) * HID + cg;
    #pragma unroll
    for (int p = 0; p < 4; ++p) {
        u32 o[4];
        #pragma unroll
        for (int q = 0; q < 4; ++q) {
            u16 lo = f2bf(gelu_f(acc[p][2 * q] + bs[2 * q]));
            u16 hi = f2bf(gelu_f(acc[p][2 * q + 1] + bs[2 * q + 1]));
            o[q] = (u32)lo | ((u32)hi << 16);
        }
        *(uint4*)(ob + (size_t)p * HID) = make_uint4(o[0], o[1], o[2], o[3]);
    }
}

// ---------------------------------------------------------------------------
extern "C" void kernel_launch(void* const* d_in, const int* in_sizes, int n_in,
                              void* d_out, int out_size, void* d_ws, size_t ws_size,
                              hipStream_t stream) {
    const float* x      = (const float*)d_in[0];
    const float* n1g    = (const float*)d_in[1];
    const float* n1b    = (const float*)d_in[2];
    const float* qkv_w  = (const float*)d_in[3];
    const float* qkv_b  = (const float*)d_in[4];
    const float* relb   = (const float*)d_in[5];
    const float* proj_w = (const float*)d_in[6];
    const float* proj_b = (const float*)d_in[7];
    const float* n2g    = (const float*)d_in[8];
    const float* n2b    = (const float*)d_in[9];
    const float* lin1_w = (const float*)d_in[10];
    const float* lin1_b = (const float*)d_in[11];
    const float* dw_w   = (const float*)d_in[12];
    const float* dw_b   = (const float*)d_in[13];
    const float* lin2_w = (const float*)d_in[14];
    const float* lin2_b = (const float*)d_in[15];
    float* out = (float*)d_out;

    // bf16 arena (9*M8 elems = 151 MB), fused-qkv layout (r17/r18, best):
    //  [0,M8):       yn (live to fused attn) -> yn2 -> h2[0:M8)
    //  [M8,2M8):     attn_out (fused kernel output; proj A)
    //  [2M8,..):     lin1_wt (live to lin1); then dead (h2 overwrites)
    //  [4M8,5M8):    x1 (steps proj..lin2)
    //  [5M8,9M8):    qkv_wt+proj_wt (to proj) -> hbuf (lin1..dwconv) -> lin2_wt
    u16* ws16 = (u16*)d_ws;
    const size_t M8 = (size_t)MTOK * CDIM;   // 8,388,608
    u16* yn      = ws16;
    u16* attn    = ws16 + M8;
    u16* x1      = ws16 + 4 * M8;
    u16* yn2     = ws16;
    u16* hbuf    = ws16 + 5 * M8;
    u16* h2      = ws16;
    u16* qkv_wt  = ws16 + 5 * M8;            // [768][256]
    u16* proj_wt = qkv_wt + 768 * 256;       // [256][256]
    u16* lin1_wt = ws16 + 2 * M8;            // [1024][256]
    u16* lin2_wt = ws16 + 5 * M8;            // [256][1024]
    float* wt9   = (float*)d_out;            // [9][1024] scratch; d_out dead
                                             // until final GEMM overwrites it

    // 0+1) merged prep + LN1: transposes + dwprep + LN1 in one launch
    prep_ln1_kernel<<<8740, 256, 0, stream>>>(
        x, n1g, n1b, yn, qkv_w, proj_w, lin1_w, dw_w,
        qkv_wt, proj_wt, lin1_wt, wt9);
    // 2+3) FUSED qkv projection + windowed attention (merged single pass)
    fused_qkv_attn_kernel<<<512, 512, 0, stream>>>(yn, qkv_wt, qkv_b, relb, attn);
    // 4) x1 = attn @ proj_w + proj_b + x   (4-wave: grid 2x256 = 512)
    mgemm_kernel<1, CDIM, float, u16><<<(CDIM / 128) * (MTOK / 128), 256, 0, stream>>>(
        attn, proj_wt, proj_b, x, x1, CDIM, CDIM / 128);
    // 5) LN2: bf16 in, bf16 out
    ln_kernel<u16, u16><<<MTOK / 4, 256, 0, stream>>>(x1, n2g, n2b, yn2);
    // 6) hbuf = gelu(yn2 @ lin1_w + lin1_b)   (8-wave: grid 4x256 = 1024)
    mgemm8_kernel<2, CDIM, float, u16><<<(HID / 256) * (MTOK / 128), 512, 0, stream>>>(
        yn2, lin1_wt, lin1_b, (const float*)nullptr, hbuf, HID, HID / 256);
    // 7) h2 = gelu(dwconv3x3(hbuf) + dw_b)
    dwconv_kernel<<<BATCH * 2048, 256, 0, stream>>>(hbuf, wt9, dw_b, h2);
    // weight prep (lin2) into dead hbuf region
    transpose_bf16_kernel<<<dim3(256 / 32, 1024 / 32), 256, 0, stream>>>(lin2_w, lin2_wt, 1024, 256);
    // 8) out = h2 @ lin2_w + lin2_b + x1   (4-wave, K=1024: grid 2x256 = 512)
    mgemm_kernel<1, HID, u16, float><<<(CDIM / 128) * (MTOK / 128), 256, 0, stream>>>(
        h2, lin2_wt, lin2_b, x1, out, CDIM, CDIM / 128);

    (void)in_sizes; (void)n_in; (void)out_size; (void)ws_size;
}

// Round 22
// 237.135 us; speedup vs baseline: 1.0856x; 1.0170x over previous
//
#include <hip/hip_runtime.h>
#include <math.h>

// Problem constants
#define BATCH 2
#define HW 128          // H == W
#define CDIM 256
#define LTOK 16384      // HW*HW
#define MTOK 32768      // BATCH*LTOK
#define HEADS 8
#define DH 32
#define WINSZ 8
#define NWIN 64         // tokens per window
#define HID 1024

typedef unsigned int  u32;
typedef unsigned short u16;   // bf16 storage

typedef __attribute__((ext_vector_type(8))) short bf16x8;
typedef __attribute__((ext_vector_type(4))) float f32x4;

__device__ __forceinline__ float gelu_f(float v) {
    return 0.5f * v * (1.f + erff(v * 0.70710678118654752f));
}

__device__ __forceinline__ u16 f2bf(float f) {
    u32 u = __float_as_uint(f);
    u32 r = (u + 0x7fffu + ((u >> 16) & 1u)) >> 16;   // round-to-nearest-even
    return (u16)r;
}

// ---- generic 4-wide load/store: fp32 or bf16 ------------------------------
__device__ __forceinline__ float4 ld4(const float* p) { return *(const float4*)p; }
__device__ __forceinline__ float4 ld4(const u16* p) {
    uint2 v = *(const uint2*)p;
    float4 r;
    r.x = __uint_as_float((v.x & 0xffffu) << 16);
    r.y = __uint_as_float(v.x & 0xffff0000u);
    r.z = __uint_as_float((v.y & 0xffffu) << 16);
    r.w = __uint_as_float(v.y & 0xffff0000u);
    return r;
}
__device__ __forceinline__ void st4(float* p, float4 v) { *(float4*)p = v; }
__device__ __forceinline__ void st4(u16* p, float4 v) {
    uint2 o;
    o.x = (u32)f2bf(v.x) | ((u32)f2bf(v.y) << 16);
    o.y = (u32)f2bf(v.z) | ((u32)f2bf(v.w) << 16);
    *(uint2*)p = o;
}
// ---- scalar load/store ----------------------------------------------------
__device__ __forceinline__ float lds1(const float* p) { return *p; }
__device__ __forceinline__ float lds1(const u16* p) { return __uint_as_float(((u32)*p) << 16); }
__device__ __forceinline__ void sts1(float* p, float v) { *p = v; }
__device__ __forceinline__ void sts1(u16* p, float v) { *p = f2bf(v); }

// ---- 8-wide bf16 load -> 8 floats -----------------------------------------
__device__ __forceinline__ void ld8bf(const u16* p, float* v) {
    uint4 r = *(const uint4*)p;
    v[0] = __uint_as_float((r.x & 0xffffu) << 16);
    v[1] = __uint_as_float(r.x & 0xffff0000u);
    v[2] = __uint_as_float((r.y & 0xffffu) << 16);
    v[3] = __uint_as_float(r.y & 0xffff0000u);
    v[4] = __uint_as_float((r.z & 0xffffu) << 16);
    v[5] = __uint_as_float(r.z & 0xffff0000u);
    v[6] = __uint_as_float((r.w & 0xffffu) << 16);
    v[7] = __uint_as_float(r.w & 0xffff0000u);
}

// async global->LDS, 16B per lane (dest = wave-uniform base + lane*16)
__device__ __forceinline__ void glds16(const u16* g, u16* l) {
    __builtin_amdgcn_global_load_lds(
        (const __attribute__((address_space(1))) unsigned int*)g,
        (__attribute__((address_space(3))) unsigned int*)l, 16, 0, 0);
}

// ---------------------------------------------------------------------------
// Merged prep + LN1 (r21) + lin2 transpose (r22): everything data-independent
// at stream head in ONE 8996-block launch. Branch is block-uniform.
//   [0,8192):     LN1 rows (4 rows / 256-thr block, fp32 in -> bf16 out)
//   [8192,8384):  qkv transpose  (N=768,  Kout=256)
//   [8384,8448):  proj transpose (N=256,  Kout=256)
//   [8448,8704):  lin1 transpose (N=1024, Kout=256)
//   [8704,8960):  lin2 transpose (N=256,  Kout=1024)  <- lin2_wt now lives at
//                 9*M8 (fresh 0.5MB slice) so it can be written at step 0
//   [8960,8996):  dwprep [1024][9] -> [9][1024]
// ---------------------------------------------------------------------------
__global__ __launch_bounds__(256) void prep_ln1_kernel(
    const float* __restrict__ x, const float* __restrict__ n1g,
    const float* __restrict__ n1b, u16* __restrict__ yn,
    const float* __restrict__ qkv_w, const float* __restrict__ proj_w,
    const float* __restrict__ lin1_w, const float* __restrict__ lin2_w,
    const float* __restrict__ dw_w,
    u16* __restrict__ qkv_wt, u16* __restrict__ proj_wt,
    u16* __restrict__ lin1_wt, u16* __restrict__ lin2_wt,
    float* __restrict__ wt9)
{
    __shared__ float t[32][33];
    int idx = blockIdx.x;
    int tid = threadIdx.x;

    if (idx < 8192) {                       // ---- LN1 ----
        int wave = tid >> 6;
        int lane = tid & 63;
        int row = idx * 4 + wave;
        const float* xr = x + (size_t)row * CDIM;
        float4 v = ld4(&xr[lane * 4]);
        float s  = v.x + v.y + v.z + v.w;
        float s2 = v.x*v.x + v.y*v.y + v.z*v.z + v.w*v.w;
        #pragma unroll
        for (int off = 32; off > 0; off >>= 1) {
            s  += __shfl_xor(s,  off);
            s2 += __shfl_xor(s2, off);
        }
        float mu   = s * (1.f / CDIM);
        float var  = s2 * (1.f / CDIM) - mu * mu;
        float rstd = rsqrtf(var + 1e-5f);
        float4 gv = *(const float4*)&n1g[lane * 4];
        float4 bv = *(const float4*)&n1b[lane * 4];
        float4 o;
        o.x = (v.x - mu) * rstd * gv.x + bv.x;
        o.y = (v.y - mu) * rstd * gv.y + bv.y;
        o.z = (v.z - mu) * rstd * gv.z + bv.z;
        o.w = (v.w - mu) * rstd * gv.w + bv.w;
        st4(&yn[(size_t)row * CDIM + lane * 4], o);
        return;
    }
    idx -= 8192;
    if (idx >= 768) {                       // ---- dwprep ----
        int j = (idx - 768) * 256 + tid;
        if (j < 9 * HID) {
            int ch = j / 9, tp = j - ch * 9;
            wt9[tp * HID + ch] = dw_w[j];
        }
        return;
    }
    const float* in; u16* outp; int N, Kout, bx, by;   // ---- transposes ----
    if (idx < 192)      { in = qkv_w;  outp = qkv_wt;  N = 768;  Kout = 256;  bx = idx % 24;        by = idx / 24; }
    else if (idx < 256) { in = proj_w; outp = proj_wt; N = 256;  Kout = 256;  bx = (idx-192) % 8;   by = (idx-192) / 8; }
    else if (idx < 512) { in = lin1_w; outp = lin1_wt; N = 1024; Kout = 256;  bx = (idx-256) % 32;  by = (idx-256) / 32; }
    else                { in = lin2_w; outp = lin2_wt; N = 256;  Kout = 1024; bx = (idx-512) % 8;   by = (idx-512) / 8; }
    int bn = bx * 32, bk = by * 32;
    int tx = tid & 31, ty = tid >> 5;
    #pragma unroll
    for (int i = 0; i < 32; i += 8)
        t[ty + i][tx] = in[(size_t)(bk + ty + i) * N + bn + tx];
    __syncthreads();
    #pragma unroll
    for (int i = 0; i < 32; i += 8)
        outp[(size_t)(bn + ty + i) * Kout + bk + tx] = f2bf(t[tx][ty + i]);
}

// ---------------------------------------------------------------------------
// LayerNorm over C=256 (LN2): one wave per row, 4 rows per 256-thr block
// ---------------------------------------------------------------------------
template<typename TI, typename TO>
__global__ __launch_bounds__(256) void ln_kernel(
    const TI* __restrict__ x, const float* __restrict__ g,
    const float* __restrict__ b, TO* __restrict__ y)
{
    int wave = threadIdx.x >> 6;
    int lane = threadIdx.x & 63;
    int row = blockIdx.x * 4 + wave;
    const TI* xr = x + (size_t)row * CDIM;
    float4 v = ld4(&xr[lane * 4]);
    float s  = v.x + v.y + v.z + v.w;
    float s2 = v.x*v.x + v.y*v.y + v.z*v.z + v.w*v.w;
    #pragma unroll
    for (int off = 32; off > 0; off >>= 1) {
        s  += __shfl_xor(s,  off);
        s2 += __shfl_xor(s2, off);
    }
    float mu   = s * (1.f / CDIM);
    float var  = s2 * (1.f / CDIM) - mu * mu;
    float rstd = rsqrtf(var + 1e-5f);
    float4 gv = *(const float4*)&g[lane * 4];
    float4 bv = *(const float4*)&b[lane * 4];
    float4 o;
    o.x = (v.x - mu) * rstd * gv.x + bv.x;
    o.y = (v.y - mu) * rstd * gv.y + bv.y;
    o.z = (v.z - mu) * rstd * gv.z + bv.z;
    o.w = (v.w - mu) * rstd * gv.w + bv.w;
    st4(&y[(size_t)row * CDIM + lane * 4], o);
}

// ---------------------------------------------------------------------------
// MFMA bf16 GEMM, 4-wave (r11 structure): 128x128 tile, BK=64, single-buffer,
// XCD-bijective block swizzle + both-sides XOR granule swizzle, scalar
// epilogue. Used for proj and lin2 (grids stay 512 blocks -> ~2 blocks/CU;
// r19 showed the 8-wave tile shrinks them to 1/CU and regresses).
// ---------------------------------------------------------------------------
template<int EPI, int K, typename TR, typename TO>
__global__ __launch_bounds__(256) void mgemm_kernel(
    const u16* __restrict__ A, const u16* __restrict__ Bt,
    const float* __restrict__ bias, const TR* __restrict__ res,
    TO* __restrict__ Cc, int N, int gx)
{
    __shared__ u16 As[128 * 64];   // 16 KB
    __shared__ u16 Bs[128 * 64];   // 16 KB

    int tid  = threadIdx.x;
    int lane = tid & 63;
    int wave = tid >> 6;
    int l15  = lane & 15;
    int hi   = lane >> 4;
    int wr = wave >> 1, wc = wave & 1;

    int nwg = gridDim.x;
    int bid = blockIdx.x;
    int swz = (bid & 7) * (nwg >> 3) + (bid >> 3);
    int bx = swz % gx, by = swz / gx;
    size_t bm = (size_t)by * 128;
    size_t bn = (size_t)bx * 128;

    int srow8 = lane >> 3;          // 0..7
    int ce    = (lane & 7) * 8;     // 0..56 (element col granule)

    int ar = wr * 64 + l15;
    int br = wc * 64 + l15;

    f32x4 acc[4][4] = {};

    for (int t = 0; t < K / 64; ++t) {
        int kt = t * 64;
        #pragma unroll
        for (int g = 0; g < 4; ++g) {
            int rowb = wave * 32 + g * 8;
            int row  = rowb + srow8;
            int col  = kt + (ce ^ ((row & 7) << 3));
            glds16(A  + (bm + row) * K + col, As + rowb * 64);
            glds16(Bt + (bn + row) * K + col, Bs + rowb * 64);
        }
        __syncthreads();

        #pragma unroll
        for (int ks = 0; ks < 2; ++ks) {
            int e = ks * 32 + hi * 8;
            bf16x8 af[4], bfv[4];
            #pragma unroll
            for (int m = 0; m < 4; ++m) {
                int row = ar + m * 16;
                af[m] = *(const bf16x8*)&As[row * 64 + (e ^ ((row & 7) << 3))];
            }
            #pragma unroll
            for (int n = 0; n < 4; ++n) {
                int row = br + n * 16;
                bfv[n] = *(const bf16x8*)&Bs[row * 64 + (e ^ ((row & 7) << 3))];
            }
            #pragma unroll
            for (int m = 0; m < 4; ++m)
                #pragma unroll
                for (int n = 0; n < 4; ++n)
                    acc[m][n] = __builtin_amdgcn_mfma_f32_16x16x32_bf16(
                        af[m], bfv[n], acc[m][n], 0, 0, 0);
        }
        __syncthreads();
    }

    int colb = (int)bn + wc * 64 + l15;
    int rowb = (int)bm + wr * 64 + hi * 4;
    #pragma unroll
    for (int n = 0; n < 4; ++n) {
        float bv = bias[colb + n * 16];
        #pragma unroll
        for (int m = 0; m < 4; ++m) {
            #pragma unroll
            for (int r = 0; r < 4; ++r) {
                int row = rowb + m * 16 + r;
                float v = acc[m][n][r] + bv;
                if (EPI == 1) v += lds1(&res[(size_t)row * N + colb + n * 16]);
                if (EPI == 2) v = gelu_f(v);
                sts1(&Cc[(size_t)row * N + colb + n * 16], v);
            }
        }
    }
}

// ---------------------------------------------------------------------------
// MFMA bf16 GEMM, 8-wave (r18 validated, lin1 ONLY): BM=128 x BN=256,
// 512 threads = 8 waves each owning the proven 64x64 / acc[4][4] / 64-VGPR
// shape. LDS 48KB; lin1's grid stays 1024 blocks -> occ 42%, total -4.7us.
// r19 lesson: only a win when the grid still oversubscribes CUs.
// ---------------------------------------------------------------------------
template<int EPI, int K, typename TR, typename TO>
__global__ __launch_bounds__(512) void mgemm8_kernel(
    const u16* __restrict__ A, const u16* __restrict__ Bt,
    const float* __restrict__ bias, const TR* __restrict__ res,
    TO* __restrict__ Cc, int N, int gx)
{
    __shared__ u16 As[128 * 64];   // 16 KB
    __shared__ u16 Bs[256 * 64];   // 32 KB

    int tid  = threadIdx.x;
    int lane = tid & 63;
    int wave = tid >> 6;            // 0..7
    int l15  = lane & 15;
    int hi   = lane >> 4;
    int wr = wave >> 2;             // 0..1 (M half)
    int wc = wave & 3;              // 0..3 (N quarter)

    int nwg = gridDim.x;
    int bid = blockIdx.x;
    int swz = (bid & 7) * (nwg >> 3) + (bid >> 3);
    int bx = swz % gx, by = swz / gx;
    size_t bm = (size_t)by * 128;
    size_t bn = (size_t)bx * 256;

    int srow8 = lane >> 3;          // 0..7
    int ce    = (lane & 7) * 8;     // 0..56 (element col granule)

    int ar = wr * 64 + l15;
    int br = wc * 64 + l15;

    f32x4 acc[4][4] = {};

    for (int t = 0; t < K / 64; ++t) {
        int kt = t * 64;
        // A: 128 rows, wave stages 16 (2 glds)
        #pragma unroll
        for (int g = 0; g < 2; ++g) {
            int rowb = wave * 16 + g * 8;
            int row  = rowb + srow8;
            int col  = kt + (ce ^ ((row & 7) << 3));
            glds16(A + (bm + row) * K + col, As + rowb * 64);
        }
        // B: 256 rows, wave stages 32 (4 glds)
        #pragma unroll
        for (int g = 0; g < 4; ++g) {
            int rowb = wave * 32 + g * 8;
            int row  = rowb + srow8;
            int col  = kt + (ce ^ ((row & 7) << 3));
            glds16(Bt + (bn + row) * K + col, Bs + rowb * 64);
        }
        __syncthreads();

        #pragma unroll
        for (int ks = 0; ks < 2; ++ks) {
            int e = ks * 32 + hi * 8;
            bf16x8 af[4], bfv[4];
            #pragma unroll
            for (int m = 0; m < 4; ++m) {
                int row = ar + m * 16;
                af[m] = *(const bf16x8*)&As[row * 64 + (e ^ ((row & 7) << 3))];
            }
            #pragma unroll
            for (int n = 0; n < 4; ++n) {
                int row = br + n * 16;
                bfv[n] = *(const bf16x8*)&Bs[row * 64 + (e ^ ((row & 7) << 3))];
            }
            #pragma unroll
            for (int m = 0; m < 4; ++m)
                #pragma unroll
                for (int n = 0; n < 4; ++n)
                    acc[m][n] = __builtin_amdgcn_mfma_f32_16x16x32_bf16(
                        af[m], bfv[n], acc[m][n], 0, 0, 0);
        }
        __syncthreads();
    }

    int colb = (int)bn + wc * 64 + l15;
    int rowb = (int)bm + wr * 64 + hi * 4;
    #pragma unroll
    for (int n = 0; n < 4; ++n) {
        float bv = bias[colb + n * 16];
        #pragma unroll
        for (int m = 0; m < 4; ++m) {
            #pragma unroll
            for (int r = 0; r < 4; ++r) {
                int row = rowb + m * 16 + r;
                float v = acc[m][n][r] + bv;
                if (EPI == 1) v += lds1(&res[(size_t)row * N + colb + n * 16]);
                if (EPI == 2) v = gelu_f(v);
                sts1(&Cc[(size_t)row * N + colb + n * 16], v);
            }
        }
    }
}

// ---------------------------------------------------------------------------
// FUSED qkv-projection + windowed attention (r17 best: 512-thr, 512 blocks,
// wave=head, ZERO barriers, single merged q/k/v projection pass).
// ---------------------------------------------------------------------------
__global__ __launch_bounds__(512) void fused_qkv_attn_kernel(
    const u16* __restrict__ yn, const u16* __restrict__ qkv_wt,
    const float* __restrict__ qkv_b, const float* __restrict__ bias_table,
    u16* __restrict__ out)
{
    __shared__ u16 lds[8][4096];   // 8 KB per wave: q@0,k@2048 -> v@0 -> P@0

    int tid  = threadIdx.x;
    int lane = tid & 63;
    int head = tid >> 6;            // wave = head
    int l15  = lane & 15;
    int hi   = lane >> 4;
    int w  = blockIdx.x;            // window 0..511
    int b  = w >> 8;
    int ww = w & 255;
    int wr = ww >> 4, wc = ww & 15;
    u16* L = lds[head];

    auto tokof = [&](int n) -> int {
        int si = (wr * WINSZ + (n >> 3) + 4) & 127;
        int sj = (wc * WINSZ + (n & 7) + 4) & 127;
        return b * LTOK + si * HW + sj;
    };
    auto labelof = [&](int n) -> int {
        int i = wr * WINSZ + (n >> 3);
        int j = wc * WINSZ + (n & 7);
        int li = (i < 120) ? 0 : (i < 124 ? 1 : 2);
        int lj = (j < 120) ? 0 : (j < 124 ? 1 : 2);
        return li * 3 + lj;
    };

    const u16* arow[4];
    #pragma unroll
    for (int m = 0; m < 4; ++m)
        arow[m] = yn + (size_t)tokof(m * 16 + l15) * CDIM + hi * 8;

    // ---- merged projection pass: q,k,v in one kb loop ----------------------
    f32x4 qa[4][2] = {}, ka[4][2] = {}, va[4][2] = {};
    __builtin_amdgcn_s_setprio(1);
    #pragma unroll
    for (int kb = 0; kb < 8; ++kb) {
        bf16x8 a[4];
        #pragma unroll
        for (int m = 0; m < 4; ++m)
            a[m] = *(const bf16x8*)(arow[m] + kb * 32);
        #pragma unroll
        for (int nf = 0; nf < 2; ++nf) {
            const u16* wp = qkv_wt +
                (size_t)(head * 32 + nf * 16 + l15) * CDIM + kb * 32 + hi * 8;
            bf16x8 bq = *(const bf16x8*)wp;                 // q rows [0,256)
            bf16x8 bk = *(const bf16x8*)(wp + 256 * CDIM);  // k rows [256,512)
            bf16x8 bv = *(const bf16x8*)(wp + 512 * CDIM);  // v rows [512,768)
            #pragma unroll
            for (int m = 0; m < 4; ++m) {
                qa[m][nf] = __builtin_amdgcn_mfma_f32_16x16x32_bf16(a[m], bq, qa[m][nf], 0, 0, 0);
                ka[m][nf] = __builtin_amdgcn_mfma_f32_16x16x32_bf16(a[m], bk, ka[m][nf], 0, 0, 0);
                va[m][nf] = __builtin_amdgcn_mfma_f32_16x16x32_bf16(a[m], bv, va[m][nf], 0, 0, 0);
            }
        }
    }
    __builtin_amdgcn_s_setprio(0);

    // ---- q,k -> LDS (swizzled), read back as A/B frags ---------------------
    #pragma unroll
    for (int nf = 0; nf < 2; ++nf) {
        int d = nf * 16 + l15;
        float bq = qkv_b[head * 32 + d];
        float bk = qkv_b[256 + head * 32 + d];
        int g = nf * 2 + (l15 >> 3);
        #pragma unroll
        for (int m = 0; m < 4; ++m)
            #pragma unroll
            for (int r = 0; r < 4; ++r) {
                int tok = m * 16 + hi * 4 + r;
                int ad = tok * 32 + ((g ^ r ^ hi) << 3) + (d & 7);
                L[ad]        = f2bf(qa[m][nf][r] + bq);
                L[2048 + ad] = f2bf(ka[m][nf][r] + bk);
            }
    }
    bf16x8 qf[4], kf[4];
    {
        int sz = (hi ^ (l15 & 3) ^ ((l15 >> 2) & 3)) << 3;
        #pragma unroll
        for (int m = 0; m < 4; ++m) {
            int ra = (m * 16 + l15) * 32 + sz;
            qf[m] = *(const bf16x8*)&L[ra];
            kf[m] = *(const bf16x8*)&L[2048 + ra];
        }
    }

    // ---- v -> LDS (overlays q region, already consumed), read V^T frags ----
    #pragma unroll
    for (int nf = 0; nf < 2; ++nf) {
        int d = nf * 16 + l15;
        float bv = qkv_b[512 + head * 32 + d];
        #pragma unroll
        for (int m = 0; m < 4; ++m)
            #pragma unroll
            for (int r = 0; r < 4; ++r) {
                int tok = m * 16 + hi * 4 + r;
                int av = d * 64 + (((tok >> 3) ^ (d & 7)) << 3) + (tok & 7);
                L[av] = f2bf(va[m][nf][r] + bv);
            }
    }
    bf16x8 vf[2][2];
    #pragma unroll
    for (int nf = 0; nf < 2; ++nf) {
        int d = nf * 16 + l15;
        #pragma unroll
        for (int ks = 0; ks < 2; ++ks) {
            int rv = d * 64 + (((ks * 4 + hi) ^ (d & 7)) << 3);
            vf[nf][ks] = *(const bf16x8*)&L[rv];
        }
    }

    // ---- QK^T --------------------------------------------------------------
    f32x4 s[4][4];
    __builtin_amdgcn_s_setprio(1);
    #pragma unroll
    for (int m = 0; m < 4; ++m)
        #pragma unroll
        for (int n = 0; n < 4; ++n) {
            f32x4 z = {0.f, 0.f, 0.f, 0.f};
            s[m][n] = __builtin_amdgcn_mfma_f32_16x16x32_bf16(qf[m], kf[n], z, 0, 0, 0);
        }
    __builtin_amdgcn_s_setprio(0);

    int klbl[4];
    #pragma unroll
    for (int n = 0; n < 4; ++n) klbl[n] = labelof(n * 16 + l15);

    // ---- softmax; P -> LDS (overlays q/k/v, all consumed) ------------------
    const float SCALE = 0.17677669529663687f;  // 1/sqrt(32)
    float inv[4][4];
    #pragma unroll
    for (int m = 0; m < 4; ++m) {
        #pragma unroll
        for (int r = 0; r < 4; ++r) {
            int q = m * 16 + hi * 4 + r;
            int qlbl = labelof(q);
            int rq = q >> 3, cq = q & 7;
            float v[4];
            #pragma unroll
            for (int n = 0; n < 4; ++n) {
                int kn = n * 16 + l15;
                int idx = (rq - (kn >> 3) + 7) * 15 + (cq - (kn & 7) + 7);
                float bv = bias_table[idx * HEADS + head];
                v[n] = s[m][n][r] * SCALE + bv + ((klbl[n] != qlbl) ? -100.f : 0.f);
            }
            float rmax = fmaxf(fmaxf(v[0], v[1]), fmaxf(v[2], v[3]));
            #pragma unroll
            for (int off = 1; off < 16; off <<= 1)
                rmax = fmaxf(rmax, __shfl_xor(rmax, off));
            float p0 = __expf(v[0] - rmax), p1 = __expf(v[1] - rmax);
            float p2 = __expf(v[2] - rmax), p3 = __expf(v[3] - rmax);
            float ls = p0 + p1 + p2 + p3;
            #pragma unroll
            for (int off = 1; off < 16; off <<= 1)
                ls += __shfl_xor(ls, off);
            inv[m][r] = 1.f / ls;
            int sw = (q & 7) << 3;
            L[q * 64 + ((0 * 16 + l15) ^ sw)] = f2bf(p0);
            L[q * 64 + ((1 * 16 + l15) ^ sw)] = f2bf(p1);
            L[q * 64 + ((2 * 16 + l15) ^ sw)] = f2bf(p2);
            L[q * 64 + ((3 * 16 + l15) ^ sw)] = f2bf(p3);
        }
    }

    // ---- PV ----------------------------------------------------------------
    f32x4 o[4][2] = {};
    __builtin_amdgcn_s_setprio(1);
    #pragma unroll
    for (int ks = 0; ks < 2; ++ks) {
        #pragma unroll
        for (int m = 0; m < 4; ++m) {
            int row = m * 16 + l15;
            int colb = (ks * 32 + hi * 8) ^ ((row & 7) << 3);
            bf16x8 pa = *(const bf16x8*)&L[row * 64 + colb];
            #pragma unroll
            for (int nf = 0; nf < 2; ++nf)
                o[m][nf] = __builtin_amdgcn_mfma_f32_16x16x32_bf16(
                    pa, vf[nf][ks], o[m][nf], 0, 0, 0);
        }
    }
    __builtin_amdgcn_s_setprio(0);

    // ---- epilogue ----------------------------------------------------------
    #pragma unroll
    for (int m = 0; m < 4; ++m) {
        #pragma unroll
        for (int r = 0; r < 4; ++r) {
            int q = m * 16 + hi * 4 + r;
            int t = tokof(q);
            u16* op = out + (size_t)t * CDIM + head * DH + l15;
            float iv = inv[m][r];
            op[0]  = f2bf(o[m][0][r] * iv);
            op[16] = f2bf(o[m][1][r] * iv);
        }
    }
}

// ---------------------------------------------------------------------------
// Depthwise 3x3 conv (NHWC, SAME zero-pad) + bias + GELU. bf16 in/out.
// XCD row-locality swizzle: each XCD owns 32 contiguous image rows so halo
// rows i±1 hit the same L2.
// ---------------------------------------------------------------------------
__global__ __launch_bounds__(256) void dwconv_kernel(
    const u16* __restrict__ h, const float* __restrict__ wt9,
    const float* __restrict__ bias, u16* __restrict__ out)
{
    int bid = blockIdx.x;
    int blk = (bid & 7) * ((int)gridDim.x >> 3) + (bid >> 3);
    int b   = blk >> 11;              // b*2048 + i*16 + jt
    int rem = blk & 2047;
    int i   = rem >> 4;
    int jt  = rem & 15;
    int cg  = (threadIdx.x & 127) * 8;           // channel base (0..1016)
    int j0  = jt * 8 + (threadIdx.x >> 7) * 4;   // first of 4 output pixels

    float acc[4][8] = {};
    const u16* base = h + (size_t)b * LTOK * HID + cg;

    #pragma unroll
    for (int di = 0; di < 3; ++di) {
        int ii = i + di - 1;
        if (ii < 0 || ii >= HW) continue;
        const u16* rowp = base + (size_t)ii * HW * HID;
        float v[6][8];
        #pragma unroll
        for (int cc = 0; cc < 6; ++cc) {
            int jj = j0 - 1 + cc;
            if (jj >= 0 && jj < HW) {
                ld8bf(&rowp[(size_t)jj * HID], v[cc]);
            } else {
                #pragma unroll
                for (int q = 0; q < 8; ++q) v[cc][q] = 0.f;
            }
        }
        #pragma unroll
        for (int t = 0; t < 3; ++t) {
            const float* wp = &wt9[(di * 3 + t) * HID + cg];
            float4 wa = *(const float4*)wp;
            float4 wb = *(const float4*)(wp + 4);
            float w[8] = {wa.x, wa.y, wa.z, wa.w, wb.x, wb.y, wb.z, wb.w};
            #pragma unroll
            for (int p = 0; p < 4; ++p)
                #pragma unroll
                for (int q = 0; q < 8; ++q)
                    acc[p][q] += v[p + t][q] * w[q];
        }
    }

    float4 ba = *(const float4*)&bias[cg];
    float4 bb = *(const float4*)&bias[cg + 4];
    float bs[8] = {ba.x, ba.y, ba.z, ba.w, bb.x, bb.y, bb.z, bb.w};
    u16* ob = out + ((size_t)b * LTOK + (size_t)i * HW + j0) * HID + cg;
    #pragma unroll
    for (int p = 0; p < 4; ++p) {
        u32 o[4];
        #pragma unroll
        for (int q = 0; q < 4; ++q) {
            u16 lo = f2bf(gelu_f(acc[p][2 * q] + bs[2 * q]));
            u16 hi = f2bf(gelu_f(acc[p][2 * q + 1] + bs[2 * q + 1]));
            o[q] = (u32)lo | ((u32)hi << 16);
        }
        *(uint4*)(ob + (size_t)p * HID) = make_uint4(o[0], o[1], o[2], o[3]);
    }
}

// ---------------------------------------------------------------------------
extern "C" void kernel_launch(void* const* d_in, const int* in_sizes, int n_in,
                              void* d_out, int out_size, void* d_ws, size_t ws_size,
                              hipStream_t stream) {
    const float* x      = (const float*)d_in[0];
    const float* n1g    = (const float*)d_in[1];
    const float* n1b    = (const float*)d_in[2];
    const float* qkv_w  = (const float*)d_in[3];
    const float* qkv_b  = (const float*)d_in[4];
    const float* relb   = (const float*)d_in[5];
    const float* proj_w = (const float*)d_in[6];
    const float* proj_b = (const float*)d_in[7];
    const float* n2g    = (const float*)d_in[8];
    const float* n2b    = (const float*)d_in[9];
    const float* lin1_w = (const float*)d_in[10];
    const float* lin1_b = (const float*)d_in[11];
    const float* dw_w   = (const float*)d_in[12];
    const float* dw_b   = (const float*)d_in[13];
    const float* lin2_w = (const float*)d_in[14];
    const float* lin2_b = (const float*)d_in[15];
    float* out = (float*)d_out;

    // bf16 arena (9*M8 + 256K elems = 151.5 MB):
    //  [0,M8):       yn (live to fused attn) -> yn2 -> h2[0:M8)
    //  [M8,2M8):     attn_out (fused kernel output; proj A) -> h2
    //  [2M8,..):     lin1_wt (live to lin1); then dead (h2 overwrites)
    //  [4M8,5M8):    x1 (steps proj..lin2)
    //  [5M8,9M8):    qkv_wt+proj_wt (to proj) -> hbuf (lin1..dwconv)
    //  [9M8,+256K):  lin2_wt (written in prep, read in final GEMM) -- fresh
    //                slice so the lin2 transpose merges into prep (r22)
    u16* ws16 = (u16*)d_ws;
    const size_t M8 = (size_t)MTOK * CDIM;   // 8,388,608
    u16* yn      = ws16;
    u16* attn    = ws16 + M8;
    u16* x1      = ws16 + 4 * M8;
    u16* yn2     = ws16;
    u16* hbuf    = ws16 + 5 * M8;
    u16* h2      = ws16;
    u16* qkv_wt  = ws16 + 5 * M8;            // [768][256]
    u16* proj_wt = qkv_wt + 768 * 256;       // [256][256]
    u16* lin1_wt = ws16 + 2 * M8;            // [1024][256]
    u16* lin2_wt = ws16 + 9 * M8;            // [256][1024] (fresh slice)
    float* wt9   = (float*)d_out;            // [9][1024] scratch; d_out dead
                                             // until final GEMM overwrites it

    // 0+1) merged prep + LN1 + ALL weight transposes + dwprep (one launch)
    prep_ln1_kernel<<<8996, 256, 0, stream>>>(
        x, n1g, n1b, yn, qkv_w, proj_w, lin1_w, lin2_w, dw_w,
        qkv_wt, proj_wt, lin1_wt, lin2_wt, wt9);
    // 2+3) FUSED qkv projection + windowed attention (merged single pass)
    fused_qkv_attn_kernel<<<512, 512, 0, stream>>>(yn, qkv_wt, qkv_b, relb, attn);
    // 4) x1 = attn @ proj_w + proj_b + x   (4-wave: grid 2x256 = 512)
    mgemm_kernel<1, CDIM, float, u16><<<(CDIM / 128) * (MTOK / 128), 256, 0, stream>>>(
        attn, proj_wt, proj_b, x, x1, CDIM, CDIM / 128);
    // 5) LN2: bf16 in, bf16 out
    ln_kernel<u16, u16><<<MTOK / 4, 256, 0, stream>>>(x1, n2g, n2b, yn2);
    // 6) hbuf = gelu(yn2 @ lin1_w + lin1_b)   (8-wave: grid 4x256 = 1024)
    mgemm8_kernel<2, CDIM, float, u16><<<(HID / 256) * (MTOK / 128), 512, 0, stream>>>(
        yn2, lin1_wt, lin1_b, (const float*)nullptr, hbuf, HID, HID / 256);
    // 7) h2 = gelu(dwconv3x3(hbuf) + dw_b)
    dwconv_kernel<<<BATCH * 2048, 256, 0, stream>>>(hbuf, wt9, dw_b, h2);
    // 8) out = h2 @ lin2_w + lin2_b + x1   (4-wave, K=1024: grid 2x256 = 512)
    mgemm_kernel<1, HID, u16, float><<<(CDIM / 128) * (MTOK / 128), 256, 0, stream>>>(
        h2, lin2_wt, lin2_b, x1, out, CDIM, CDIM / 128);

    (void)in_sizes; (void)n_in; (void)out_size; (void)ws_size;
}